// Round 7
// baseline (485.092 us; speedup 1.0000x reference)
//
#include <hip/hip_runtime.h>

#define NN   100000
#define NE   1600000
#define NT   1700000      // NE + NN self-loops
#define BSH  8            // 256 nodes per bucket
#define BSZ  256
#define NBK  391          // ceil(NN/256)
#define TA   4096         // edges per binA block
#define NBA  391          // ceil(NE/TA)
#define NBH  391          // ceil((NE/4)/1024)
#define CAPB 6400         // LDS staging capacity (entries) in k_binB

typedef _Float16 half_t;
typedef __attribute__((ext_vector_type(2))) _Float16 f16x2;
typedef __attribute__((ext_vector_type(4))) _Float16 f16x4;
typedef __attribute__((ext_vector_type(8))) _Float16 f16x8;
typedef __attribute__((ext_vector_type(4))) float    f32x4;

// ============================ prep: transpose weights to fp16 [n][k], zero bcnt ============================
// blocks 0-3: W1 (2x2 64-tiles); 4-7: W2; 8-9: Wc (k-tiles, n padded 40->48); 10: zero bcnt
__global__ __launch_bounds__(256) void k_prep(const float* __restrict__ W1, const float* __restrict__ W2,
                                              const float* __restrict__ Wc, half_t* __restrict__ WT1,
                                              half_t* __restrict__ WT2, half_t* __restrict__ WTc,
                                              int* __restrict__ bcnt) {
  int b = blockIdx.x;
  int t = threadIdx.x;
  if (b == 10) {
    for (int i = t; i < NBK; i += 256) bcnt[i] = 0;
    return;
  }
  __shared__ float tile[64][65];
  const float* W;
  half_t* WT;
  int k0, n0, N, NTr;
  if (b < 4)       { W = W1; WT = WT1; k0 = (b >> 1) * 64; n0 = (b & 1) * 64; N = 128; NTr = 128; }
  else if (b < 8)  { int bb = b - 4; W = W2; WT = WT2; k0 = (bb >> 1) * 64; n0 = (bb & 1) * 64; N = 128; NTr = 128; }
  else             { int bb = b - 8; W = Wc; WT = WTc; k0 = bb * 64; n0 = 0; N = 40; NTr = 48; }
  int col = t & 63, r4 = t >> 6;
#pragma unroll
  for (int i = 0; i < 16; i++) {
    int row = r4 * 16 + i;                       // k-local
    float v = 0.f;
    if (n0 + col < N) v = W[(size_t)(k0 + row) * N + n0 + col];
    tile[row][col] = v;                          // tile[k][n]
  }
  __syncthreads();
#pragma unroll
  for (int i = 0; i < 16; i++) {
    int nrow = r4 * 16 + i;                      // n-local
    if (n0 + nrow < NTr) WT[(size_t)(n0 + nrow) * 128 + k0 + col] = (half_t)tile[col][nrow];
  }
}

// ============================ bucket histogram (int4 loads) ============================
__global__ __launch_bounds__(256) void k_bhist(const int* __restrict__ dst, int* __restrict__ bcnt) {
  __shared__ int h[NBK];
  int t = threadIdx.x;
  for (int i = t; i < NBK; i += 256) h[i] = 0;
  __syncthreads();
  const int4* d4 = (const int4*)dst;
  int base = blockIdx.x * 1024;
#pragma unroll
  for (int i = 0; i < 4; i++) {
    int idx = base + t + i * 256;
    if (idx < NE / 4) {
      int4 v = d4[idx];
      atomicAdd(&h[v.x >> BSH], 1);
      atomicAdd(&h[v.y >> BSH], 1);
      atomicAdd(&h[v.z >> BSH], 1);
      atomicAdd(&h[v.w >> BSH], 1);
    }
  }
  __syncthreads();
  for (int i = t; i < NBK; i += 256) {
    int c = h[i];
    if (c > 0) atomicAdd(&bcnt[i], c);
  }
}

// scan bucket counts (2 elems/thread) -> ebase (edges, for bpk), abase (edges+loops), bcur
__global__ __launch_bounds__(256) void k_bscan(const int* __restrict__ bcnt, int* __restrict__ ebase,
                                               int* __restrict__ abase, int* __restrict__ bcur,
                                               int* __restrict__ offs) {
  __shared__ int sh[256];
  int t = threadIdx.x;
  int i0 = 2 * t, i1 = 2 * t + 1;
  int ve0 = (i0 < NBK) ? bcnt[i0] : 0;
  int ve1 = (i1 < NBK) ? bcnt[i1] : 0;
  int nl0 = (i0 < NBK) ? min(BSZ, NN - (i0 << BSH)) : 0;
  int nl1 = (i1 < NBK) ? min(BSZ, NN - (i1 << BSH)) : 0;
  {
    int s2 = ve0 + ve1;
    int x = s2;
    sh[t] = x;
    for (int off = 1; off < 256; off <<= 1) {
      __syncthreads();
      int y = (t >= off) ? sh[t - off] : 0;
      __syncthreads();
      x += y;
      sh[t] = x;
    }
    int ex = x - s2;
    if (i0 < NBK) { ebase[i0] = ex; bcur[i0] = ex; }
    if (i1 < NBK) { ebase[i1] = ex + ve0; bcur[i1] = ex + ve0; }
  }
  __syncthreads();
  {
    int a0 = ve0 + nl0, a1 = ve1 + nl1;
    int s2 = a0 + a1;
    int x = s2;
    sh[t] = x;
    for (int off = 1; off < 256; off <<= 1) {
      __syncthreads();
      int y = (t >= off) ? sh[t - off] : 0;
      __syncthreads();
      x += y;
      sh[t] = x;
    }
    int ex = x - s2;
    if (i0 < NBK) abase[i0] = ex;
    if (i1 < NBK) abase[i1] = ex + a0;
  }
  if (t == 0) offs[NN] = NT;
}

// ============================ pass A: bin edges by bucket ============================
__global__ __launch_bounds__(256) void k_binA(const int* __restrict__ src, const int* __restrict__ dst,
                                              int* __restrict__ bcur, unsigned int* __restrict__ bpk) {
  __shared__ int hist[NBK];
  __shared__ int hscan[NBK];
  __shared__ int gbase[NBK];
  __shared__ int cnt[NBK];
  __shared__ int ssc[256];
  __shared__ unsigned int staged[TA];
  int t = threadIdx.x;
  int e0 = blockIdx.x * TA;
  for (int i = t; i < NBK; i += 256) { hist[i] = 0; cnt[i] = 0; }
  __syncthreads();
#pragma unroll
  for (int i = 0; i < TA / 256; i++) {
    int e = e0 + t + i * 256;
    if (e < NE) atomicAdd(&hist[dst[e] >> BSH], 1);
  }
  __syncthreads();
  // exclusive scan of hist (2 elems/thread)
  {
    int v0 = (2 * t < NBK) ? hist[2 * t] : 0;
    int v1 = (2 * t + 1 < NBK) ? hist[2 * t + 1] : 0;
    int x = v0 + v1;
    ssc[t] = x;
    for (int off = 1; off < 256; off <<= 1) {
      __syncthreads();
      int y = (t >= off) ? ssc[t - off] : 0;
      __syncthreads();
      x += y;
      ssc[t] = x;
    }
    int ex = x - (v0 + v1);
    if (2 * t < NBK) { hscan[2 * t] = ex; if (v0 > 0) gbase[2 * t] = atomicAdd(&bcur[2 * t], v0); }
    if (2 * t + 1 < NBK) { hscan[2 * t + 1] = ex + v0; if (v1 > 0) gbase[2 * t + 1] = atomicAdd(&bcur[2 * t + 1], v1); }
  }
  __syncthreads();
#pragma unroll
  for (int i = 0; i < TA / 256; i++) {
    int e = e0 + t + i * 256;
    if (e < NE) {
      int d = dst[e];
      int b = d >> BSH;
      int pos = hscan[b] + atomicAdd(&cnt[b], 1);
      staged[pos] = ((unsigned int)src[e] << BSH) | (unsigned int)(d & (BSZ - 1));
    }
  }
  __syncthreads();
  int wave = t >> 6, lane = t & 63;
  for (int b = wave; b < NBK; b += 4) {
    int c = hist[b];
    if (c > 0) {
      int lo = hscan[b], gb = gbase[b];
      for (int j = lane; j < c; j += 64) bpk[gb + j] = staged[lo + j];
    }
  }
}

// ============================ pass B: sort bucket by dst, add self-loops, emit offs + adj ==========
__global__ __launch_bounds__(256) void k_binB(const unsigned int* __restrict__ bpk,
                                              const int* __restrict__ bcnt,
                                              const int* __restrict__ ebase,
                                              const int* __restrict__ abase,
                                              int* __restrict__ offs, int* __restrict__ adj) {
  __shared__ int lhist[BSZ];
  __shared__ int lscan[BSZ];
  __shared__ int lcur[BSZ];
  __shared__ unsigned int staged[CAPB];
  int b = blockIdx.x;
  int t = threadIdx.x;
  int nbeg = b << BSH;
  int nloc = min(BSZ, NN - nbeg);
  int ebeg = ebase[b];
  int ecnt = bcnt[b];
  int aeg = abase[b];
  int total = ecnt + nloc;
  lhist[t] = (t < nloc) ? 1 : 0;   // self-loop occupies slot 0 of each node's segment
  lcur[t] = 1;
  __syncthreads();
  for (int i = t; i < ecnt; i += 256) atomicAdd(&lhist[bpk[ebeg + i] & (BSZ - 1)], 1);
  __syncthreads();
  {
    int v = lhist[t];
    int x = v;
    lscan[t] = x;
    for (int off = 1; off < 256; off <<= 1) {
      __syncthreads();
      int y = (t >= off) ? lscan[t - off] : 0;
      __syncthreads();
      x += y;
      lscan[t] = x;
    }
    __syncthreads();
    lscan[t] = x - v;
  }
  __syncthreads();
  if (t < nloc) {
    offs[nbeg + t] = aeg + lscan[t];
    staged[lscan[t]] = (unsigned int)(nbeg + t);   // self-loop: src = node itself
  }
  __syncthreads();
  for (int i = t; i < ecnt; i += 256) {
    unsigned int v = bpk[ebeg + i];
    int dl = v & (BSZ - 1);
    int idx = lscan[dl] + atomicAdd(&lcur[dl], 1);
    unsigned int s = v >> BSH;
    if (idx < CAPB) staged[idx] = s;
    else adj[aeg + idx] = (int)s;  // statistically never
  }
  __syncthreads();
  int lim = min(total, CAPB);
  for (int i = t; i < lim; i += 256) adj[aeg + i] = (int)staged[i];
}

// ============================ edge weights (flat, thread-per-node) ============================
__global__ __launch_bounds__(256) void k_edgew(const int* __restrict__ adj, const int* __restrict__ offs,
                                               const float* __restrict__ asrc, const float* __restrict__ adst,
                                               half_t* __restrict__ wh) {
  int n = blockIdx.x * 256 + threadIdx.x;
  if (n >= NN) return;
  f32x4 ad = *(const f32x4*)(adst + (size_t)n * 4);
  int beg = offs[n], end = offs[n + 1];
  int e = beg;
  for (; e + 1 < end; e += 2) {
    int s0 = adj[e], s1 = adj[e + 1];
    f32x4 a0 = *(const f32x4*)(asrc + (size_t)s0 * 4);
    f32x4 a1 = *(const f32x4*)(asrc + (size_t)s1 * 4);
    f16x4 w0, w1;
#pragma unroll
    for (int h = 0; h < 4; h++) {
      float e0 = a0[h] + ad[h];
      float e1 = a1[h] + ad[h];
      e0 = (e0 > 0.f) ? e0 : 0.2f * e0;
      e1 = (e1 > 0.f) ? e1 : 0.2f * e1;
      w0[h] = (half_t)__expf(e0);
      w1[h] = (half_t)__expf(e1);
    }
    *(f16x4*)(wh + (size_t)e * 4) = w0;
    *(f16x4*)(wh + (size_t)(e + 1) * 4) = w1;
  }
  if (e < end) {
    int s = adj[e];
    f32x4 a0 = *(const f32x4*)(asrc + (size_t)s * 4);
    f16x4 w0;
#pragma unroll
    for (int h = 0; h < 4; h++) {
      float e0 = a0[h] + ad[h];
      e0 = (e0 > 0.f) ? e0 : 0.2f * e0;
      w0[h] = (half_t)__expf(e0);
    }
    *(f16x4*)(wh + (size_t)e * 4) = w0;
  }
}

// ============================ per-node gather aggregation ============================
// one wave per dst node; 16 lanes x half8 per row; 4 edges in flight; 1-deep prefetch; inline wsum.
__global__ __launch_bounds__(256) void k_aggregate(const half_t* __restrict__ H, const int* __restrict__ offs,
                                                   const int* __restrict__ adj, const half_t* __restrict__ wh,
                                                   const float* __restrict__ bias, half_t* __restrict__ out) {
  int n = blockIdx.x * 4 + (threadIdx.x >> 6);
  if (n >= NN) return;
  int lane = threadIdx.x & 63;
  int l15 = lane & 15, g = lane >> 4;
  int head = l15 >> 2;
  float acc[8] = {0.f, 0.f, 0.f, 0.f, 0.f, 0.f, 0.f, 0.f};
  float wsum = 0.f;
  int beg = offs[n], end = offs[n + 1];
  int i = beg + g;
  int s = 0;
  float w = 0.f;
  if (i < end) {
    s = adj[i];
    w = (float)wh[(size_t)i * 4 + head];
  }
  while (i < end) {
    int inext = i + 4;
    int snext = 0;
    float wn = 0.f;
    if (inext < end) {             // prefetch: independent of this iter's use
      snext = adj[inext];
      wn = (float)wh[(size_t)inext * 4 + head];
    }
    f16x8 hv = *(const f16x8*)(H + (size_t)s * 128 + l15 * 8);
    wsum += w;
#pragma unroll
    for (int j = 0; j < 8; j++) acc[j] += w * (float)hv[j];
    s = snext; w = wn; i = inext;
  }
#pragma unroll
  for (int m = 16; m < 64; m <<= 1) {
    wsum += __shfl_xor(wsum, m, 64);
#pragma unroll
    for (int j = 0; j < 8; j++) acc[j] += __shfl_xor(acc[j], m, 64);
  }
  float scale = 1.0f / (wsum + 1e-16f);
  float o0 = acc[0], o1 = acc[1];
  if (g == 1) { o0 = acc[2]; o1 = acc[3]; }
  if (g == 2) { o0 = acc[4]; o1 = acc[5]; }
  if (g == 3) { o0 = acc[6]; o1 = acc[7]; }
  int ch = l15 * 8 + g * 2;
  o0 = fmaxf(o0 * scale + bias[ch], 0.f);
  o1 = fmaxf(o1 * scale + bias[ch + 1], 0.f);
  f16x2 o;
  o[0] = (half_t)o0;
  o[1] = (half_t)o1;
  *(f16x2*)(out + (size_t)n * 128 + ch) = o;
}

// ============================ MFMA GEMM + attention logits ============================
// H(fp16 node-major) = fp16(X) @ W (W pre-transposed fp16 [n][k]); asrc/adst from C-fragments.
template <typename T>
__global__ __launch_bounds__(256) void k_gemm_att(const T* __restrict__ X, const half_t* __restrict__ WT,
                                                  const float* __restrict__ atts, const float* __restrict__ attd,
                                                  half_t* __restrict__ H, float* __restrict__ asrc,
                                                  float* __restrict__ adst) {
  __shared__ __align__(16) half_t Xt[128 * 40];   // [row][k], stride 40 halves
  __shared__ __align__(16) half_t Wt[128 * 40];   // [n][k], stride 40 halves
  int t = threadIdx.x;
  int wave = t >> 6, lane = t & 63;
  int l15 = lane & 15, quad = lane >> 4;
  int rb = blockIdx.x * 128;

  f32x4 acc[2][8];
#pragma unroll
  for (int rt = 0; rt < 2; rt++)
#pragma unroll
    for (int ct = 0; ct < 8; ct++) acc[rt][ct] = (f32x4){0.f, 0.f, 0.f, 0.f};

  for (int k0 = 0; k0 < 128; k0 += 32) {
    __syncthreads();
    if constexpr (sizeof(T) == 4) {
#pragma unroll
      for (int i = 0; i < 4; i++) {
        int lin = i * 256 + t;
        int row = lin >> 3;
        int c4 = (lin & 7) * 4;
        float4 v = make_float4(0.f, 0.f, 0.f, 0.f);
        int gr = rb + row;
        if (gr < NN) v = *(const float4*)((const float*)X + (size_t)gr * 128 + k0 + c4);
        f16x4 hv;
        hv[0] = (half_t)v.x; hv[1] = (half_t)v.y; hv[2] = (half_t)v.z; hv[3] = (half_t)v.w;
        *(f16x4*)(Xt + row * 40 + c4) = hv;
      }
    } else {
#pragma unroll
      for (int i = 0; i < 2; i++) {
        int lin = i * 256 + t;
        int row = lin >> 2;
        int c8 = (lin & 3) * 8;
        f16x8 hv = (f16x8)(half_t)0;
        int gr = rb + row;
        if (gr < NN) hv = *(const f16x8*)((const half_t*)X + (size_t)gr * 128 + k0 + c8);
        *(f16x8*)(Xt + row * 40 + c8) = hv;
      }
    }
    // W^T tile staging: coalesced f16x8 loads, contiguous vector LDS writes (no conflicts)
#pragma unroll
    for (int i = 0; i < 2; i++) {
      int lin = i * 256 + t;
      int row = lin >> 2;
      int c8 = (lin & 3) * 8;
      *(f16x8*)(Wt + row * 40 + c8) = *(const f16x8*)(WT + (size_t)row * 128 + k0 + c8);
    }
    __syncthreads();

    f16x8 a0 = *(const f16x8*)(Xt + (wave * 32 + l15) * 40 + quad * 8);
    f16x8 a1 = *(const f16x8*)(Xt + (wave * 32 + 16 + l15) * 40 + quad * 8);
#pragma unroll
    for (int ct = 0; ct < 8; ct++) {
      f16x8 b = *(const f16x8*)(Wt + (ct * 16 + l15) * 40 + quad * 8);
      acc[0][ct] = __builtin_amdgcn_mfma_f32_16x16x32_f16(a0, b, acc[0][ct], 0, 0, 0);
      acc[1][ct] = __builtin_amdgcn_mfma_f32_16x16x32_f16(a1, b, acc[1][ct], 0, 0, 0);
    }
  }

  // ---- store H node-major fp16 ----
#pragma unroll
  for (int rt = 0; rt < 2; rt++) {
    int rbase = rb + wave * 32 + rt * 16 + quad * 4;
#pragma unroll
    for (int reg = 0; reg < 4; reg++) {
      int row = rbase + reg;
      if (row < NN) {
#pragma unroll
        for (int ct = 0; ct < 8; ct++) {
          H[(size_t)row * 128 + ct * 16 + l15] = (half_t)acc[rt][ct][reg];
        }
      }
    }
  }

  // ---- attention logits ----
  float s_lo[4], s_hi[4], d_lo[4], d_hi[4];
#pragma unroll
  for (int h = 0; h < 4; h++) {
    s_lo[h] = atts[h * 32 + l15];
    s_hi[h] = atts[h * 32 + 16 + l15];
    d_lo[h] = attd[h * 32 + l15];
    d_hi[h] = attd[h * 32 + 16 + l15];
  }
#pragma unroll
  for (int rt = 0; rt < 2; rt++) {
    float ps[4][4], pd[4][4];  // [reg][head]
#pragma unroll
    for (int reg = 0; reg < 4; reg++)
#pragma unroll
      for (int h = 0; h < 4; h++) {
        ps[reg][h] = acc[rt][2 * h][reg] * s_lo[h] + acc[rt][2 * h + 1][reg] * s_hi[h];
        pd[reg][h] = acc[rt][2 * h][reg] * d_lo[h] + acc[rt][2 * h + 1][reg] * d_hi[h];
      }
#pragma unroll
    for (int m = 1; m < 16; m <<= 1) {
#pragma unroll
      for (int reg = 0; reg < 4; reg++)
#pragma unroll
        for (int h = 0; h < 4; h++) {
          ps[reg][h] += __shfl_xor(ps[reg][h], m, 64);
          pd[reg][h] += __shfl_xor(pd[reg][h], m, 64);
        }
    }
    float vs = 0.f, vd = 0.f;
#pragma unroll
    for (int reg = 0; reg < 4; reg++)
#pragma unroll
      for (int h = 0; h < 4; h++) {
        if (l15 == reg * 4 + h) { vs = ps[reg][h]; vd = pd[reg][h]; }
      }
    int row = rb + wave * 32 + rt * 16 + quad * 4 + (l15 >> 2);
    int h = l15 & 3;
    if (row < NN) {
      asrc[row * 4 + h] = vs;
      adst[row * 4 + h] = vd;
    }
  }
}

// ============================ classifier (MFMA, Wc pre-transposed, N padded to 48) ============================
__global__ __launch_bounds__(256) void k_classifier(const half_t* __restrict__ Hf, const half_t* __restrict__ WTc,
                                                    const float* __restrict__ bc, float* __restrict__ out) {
  __shared__ __align__(16) half_t Xt[128 * 40];
  __shared__ __align__(16) half_t Wt[48 * 40];
  int t = threadIdx.x;
  int wave = t >> 6, lane = t & 63;
  int l15 = lane & 15, quad = lane >> 4;
  int rb = blockIdx.x * 128;

  f32x4 acc[2][3];
#pragma unroll
  for (int rt = 0; rt < 2; rt++)
#pragma unroll
    for (int ct = 0; ct < 3; ct++) acc[rt][ct] = (f32x4){0.f, 0.f, 0.f, 0.f};

  for (int k0 = 0; k0 < 128; k0 += 32) {
    __syncthreads();
#pragma unroll
    for (int i = 0; i < 2; i++) {
      int lin = i * 256 + t;
      int row = lin >> 2;
      int c8 = (lin & 3) * 8;
      f16x8 hv = (f16x8)(half_t)0;
      int gr = rb + row;
      if (gr < NN) hv = *(const f16x8*)(Hf + (size_t)gr * 128 + k0 + c8);
      *(f16x8*)(Xt + row * 40 + c8) = hv;
    }
    if (t < 192) {
      int row = t >> 2;
      int c8 = (t & 3) * 8;
      *(f16x8*)(Wt + row * 40 + c8) = *(const f16x8*)(WTc + (size_t)row * 128 + k0 + c8);
    }
    __syncthreads();

    f16x8 a0 = *(const f16x8*)(Xt + (wave * 32 + l15) * 40 + quad * 8);
    f16x8 a1 = *(const f16x8*)(Xt + (wave * 32 + 16 + l15) * 40 + quad * 8);
#pragma unroll
    for (int ct = 0; ct < 3; ct++) {
      f16x8 b = *(const f16x8*)(Wt + (ct * 16 + l15) * 40 + quad * 8);
      acc[0][ct] = __builtin_amdgcn_mfma_f32_16x16x32_f16(a0, b, acc[0][ct], 0, 0, 0);
      acc[1][ct] = __builtin_amdgcn_mfma_f32_16x16x32_f16(a1, b, acc[1][ct], 0, 0, 0);
    }
  }

#pragma unroll
  for (int rt = 0; rt < 2; rt++) {
#pragma unroll
    for (int ct = 0; ct < 3; ct++) {
      int col = ct * 16 + l15;
      if (col < 40) {
        float bv = bc[col];
#pragma unroll
        for (int reg = 0; reg < 4; reg++) {
          int row = rb + wave * 32 + rt * 16 + quad * 4 + reg;
          if (row < NN) out[(size_t)row * 40 + col] = acc[rt][ct][reg] + bv;
        }
      }
    }
  }
}

// ============================ launch ============================

extern "C" void kernel_launch(void* const* d_in, const int* in_sizes, int n_in,
                              void* d_out, int out_size, void* d_ws, size_t ws_size,
                              hipStream_t stream) {
  const float* x   = (const float*)d_in[0];
  const int*   ei  = (const int*)d_in[1];
  const float* W1  = (const float*)d_in[2];
  const float* as1 = (const float*)d_in[3];
  const float* ad1 = (const float*)d_in[4];
  const float* b1  = (const float*)d_in[5];
  const float* W2  = (const float*)d_in[6];
  const float* as2 = (const float*)d_in[7];
  const float* ad2 = (const float*)d_in[8];
  const float* b2  = (const float*)d_in[9];
  const float* Wc  = (const float*)d_in[10];
  const float* bc  = (const float*)d_in[11];
  float* out = (float*)d_out;

  const int* esrc = ei;
  const int* edst = ei + NE;

  char* w = (char*)d_ws;
  auto alloc = [&](size_t bytes) {
    void* p = (void*)w;
    w += (bytes + 255) & ~(size_t)255;
    return p;
  };
  half_t* A   = (half_t*)alloc(sizeof(half_t) * (size_t)NN * 128);  // node-major gather target
  half_t* B   = (half_t*)alloc(sizeof(half_t) * (size_t)NN * 128);  // node-major layer output
  float* asrc = (float*)alloc(sizeof(float) * (size_t)NN * 4);
  float* adst = (float*)alloc(sizeof(float) * (size_t)NN * 4);
  int* offs   = (int*)alloc(sizeof(int) * (NN + 1));
  unsigned int* bpk = (unsigned int*)alloc(sizeof(unsigned int) * NE);
  int* adj    = (int*)alloc(sizeof(int) * NT);
  half_t* wh  = (half_t*)alloc(sizeof(half_t) * (size_t)NT * 4);
  half_t* WT1 = (half_t*)alloc(sizeof(half_t) * 128 * 128);
  half_t* WT2 = (half_t*)alloc(sizeof(half_t) * 128 * 128);
  half_t* WTc = (half_t*)alloc(sizeof(half_t) * 48 * 128);
  int* bcnt   = (int*)alloc(sizeof(int) * NBK);
  int* ebase  = (int*)alloc(sizeof(int) * NBK);
  int* abase  = (int*)alloc(sizeof(int) * NBK);
  int* bcur   = (int*)alloc(sizeof(int) * NBK);

  // ---- prep (weight transposes + bcnt zero) & CSR build ----
  k_prep<<<11, 256, 0, stream>>>(W1, W2, Wc, WT1, WT2, WTc, bcnt);
  k_bhist<<<NBH, 256, 0, stream>>>(edst, bcnt);
  k_bscan<<<1, 256, 0, stream>>>(bcnt, ebase, abase, bcur, offs);
  k_binA<<<NBA, 256, 0, stream>>>(esrc, edst, bcur, bpk);
  k_binB<<<NBK, 256, 0, stream>>>(bpk, bcnt, ebase, abase, offs, adj);

  // ---- layer 1 ----
  k_gemm_att<float><<<(NN + 127) / 128, 256, 0, stream>>>(x, WT1, as1, ad1, A, asrc, adst);
  k_edgew<<<(NN + 255) / 256, 256, 0, stream>>>(adj, offs, asrc, adst, wh);
  k_aggregate<<<(NN + 3) / 4, 256, 0, stream>>>(A, offs, adj, wh, b1, B);

  // ---- layer 2 ----
  k_gemm_att<half_t><<<(NN + 127) / 128, 256, 0, stream>>>(B, WT2, as2, ad2, A, asrc, adst);
  k_edgew<<<(NN + 255) / 256, 256, 0, stream>>>(adj, offs, asrc, adst, wh);
  k_aggregate<<<(NN + 3) / 4, 256, 0, stream>>>(A, offs, adj, wh, b2, B);

  // ---- classifier ----
  k_classifier<<<(NN + 127) / 128, 256, 0, stream>>>(B, WTc, bc, out);
}

// Round 8
// 442.639 us; speedup vs baseline: 1.0959x; 1.0959x over previous
//
#include <hip/hip_runtime.h>

#define NN   100000
#define NE   1600000
#define NT   1700000      // NE + NN self-loops
#define BSH  8            // 256 nodes per bucket
#define BSZ  256
#define NBK  391          // ceil(NN/256)
#define TA   4096         // edges per binA block
#define NBA  391          // ceil(NE/TA)
#define CAPB 6400         // LDS staging capacity (entries) in k_binB
#define NBG  782          // gemm blocks in k_front
#define NPREP 6           // W2 (4 tiles) + Wc (2 tiles)
#define NBH2 128          // partial-histogram blocks
#define EPB  12500        // edges per hist block (NE/NBH2)

typedef _Float16 half_t;
typedef __attribute__((ext_vector_type(2))) _Float16 f16x2;
typedef __attribute__((ext_vector_type(4))) _Float16 f16x4;
typedef __attribute__((ext_vector_type(8))) _Float16 f16x8;
typedef __attribute__((ext_vector_type(4))) float    f32x4;

// ============================ K1: fused front ============================
// blocks [0,782): gemm1 (fp32 X @ fp32 W1 -> H fp16 + logits)
// blocks [782,788): transpose W2/Wc to fp16 [n][k]
// blocks [788,916): per-block partial dst-histogram -> bh[bucket*128+blk] (no atomics/init)
__global__ __launch_bounds__(256) void k_front(const float* __restrict__ X, const float* __restrict__ W1,
                                               const float* __restrict__ atts, const float* __restrict__ attd,
                                               half_t* __restrict__ H, float* __restrict__ asrc,
                                               float* __restrict__ adst,
                                               const float* __restrict__ W2, const float* __restrict__ Wc,
                                               half_t* __restrict__ WT2, half_t* __restrict__ WTc,
                                               const int* __restrict__ dst, int* __restrict__ bh) {
  __shared__ __align__(16) char smem[20480];
  int t = threadIdx.x;
  int bid = blockIdx.x;

  if (bid >= NBG + NPREP) {
    // ---- partial histogram role ----
    int hb = bid - NBG - NPREP;
    int* h = (int*)smem;
    for (int i = t; i < NBK; i += 256) h[i] = 0;
    __syncthreads();
    const int4* d4 = (const int4*)dst;
    int base = hb * (EPB / 4);
#pragma unroll
    for (int i = 0; i < (EPB / 4 + 255) / 256; i++) {
      int idx = t + i * 256;
      if (idx < EPB / 4) {
        int4 v = d4[base + idx];
        atomicAdd(&h[v.x >> BSH], 1);
        atomicAdd(&h[v.y >> BSH], 1);
        atomicAdd(&h[v.z >> BSH], 1);
        atomicAdd(&h[v.w >> BSH], 1);
      }
    }
    __syncthreads();
    for (int i = t; i < NBK; i += 256) bh[i * NBH2 + hb] = h[i];
    return;
  }

  if (bid >= NBG) {
    // ---- weight transpose role ----
    int b = bid - NBG;
    float (*tile)[65] = (float(*)[65])smem;  // 64x65 fp32 = 16.6KB
    const float* W;
    half_t* WT;
    int k0, n0, N, NTr;
    if (b < 4) { W = W2; WT = WT2; k0 = (b >> 1) * 64; n0 = (b & 1) * 64; N = 128; NTr = 128; }
    else       { int bb = b - 4; W = Wc; WT = WTc; k0 = bb * 64; n0 = 0; N = 40; NTr = 48; }
    int col = t & 63, r4 = t >> 6;
#pragma unroll
    for (int i = 0; i < 16; i++) {
      int row = r4 * 16 + i;                       // k-local
      float v = 0.f;
      if (n0 + col < N) v = W[(size_t)(k0 + row) * N + n0 + col];
      tile[row][col] = v;
    }
    __syncthreads();
#pragma unroll
    for (int i = 0; i < 16; i++) {
      int nrow = r4 * 16 + i;                      // n-local
      if (n0 + nrow < NTr) WT[(size_t)(n0 + nrow) * 128 + k0 + col] = (half_t)tile[col][nrow];
    }
    return;
  }

  // ---- gemm1 role ----
  half_t* Xt = (half_t*)smem;          // [128][40]
  half_t* Wt = Xt + 128 * 40;          // [n][k] [128][40]
  int wave = t >> 6, lane = t & 63;
  int l15 = lane & 15, quad = lane >> 4;
  int rb = bid * 128;

  f32x4 acc[2][8];
#pragma unroll
  for (int rt = 0; rt < 2; rt++)
#pragma unroll
    for (int ct = 0; ct < 8; ct++) acc[rt][ct] = (f32x4){0.f, 0.f, 0.f, 0.f};

  for (int k0 = 0; k0 < 128; k0 += 32) {
    __syncthreads();
#pragma unroll
    for (int i = 0; i < 4; i++) {
      int lin = i * 256 + t;
      int row = lin >> 3;
      int c4 = (lin & 7) * 4;
      float4 v = make_float4(0.f, 0.f, 0.f, 0.f);
      int gr = rb + row;
      if (gr < NN) v = *(const float4*)(X + (size_t)gr * 128 + k0 + c4);
      f16x4 hv;
      hv[0] = (half_t)v.x; hv[1] = (half_t)v.y; hv[2] = (half_t)v.z; hv[3] = (half_t)v.w;
      *(f16x4*)(Xt + row * 40 + c4) = hv;
    }
    // W1 tile: W[k0+kr][n] -> Wt[n][kr]
#pragma unroll
    for (int i = 0; i < 4; i++) {
      int lin = i * 256 + t;
      int kr = lin >> 5;
      int n4 = (lin & 31) * 4;
      float4 v = *(const float4*)(W1 + (size_t)(k0 + kr) * 128 + n4);
      Wt[(n4 + 0) * 40 + kr] = (half_t)v.x;
      Wt[(n4 + 1) * 40 + kr] = (half_t)v.y;
      Wt[(n4 + 2) * 40 + kr] = (half_t)v.z;
      Wt[(n4 + 3) * 40 + kr] = (half_t)v.w;
    }
    __syncthreads();

    f16x8 a0 = *(const f16x8*)(Xt + (wave * 32 + l15) * 40 + quad * 8);
    f16x8 a1 = *(const f16x8*)(Xt + (wave * 32 + 16 + l15) * 40 + quad * 8);
#pragma unroll
    for (int ct = 0; ct < 8; ct++) {
      f16x8 b = *(const f16x8*)(Wt + (ct * 16 + l15) * 40 + quad * 8);
      acc[0][ct] = __builtin_amdgcn_mfma_f32_16x16x32_f16(a0, b, acc[0][ct], 0, 0, 0);
      acc[1][ct] = __builtin_amdgcn_mfma_f32_16x16x32_f16(a1, b, acc[1][ct], 0, 0, 0);
    }
  }

#pragma unroll
  for (int rt = 0; rt < 2; rt++) {
    int rbase = rb + wave * 32 + rt * 16 + quad * 4;
#pragma unroll
    for (int reg = 0; reg < 4; reg++) {
      int row = rbase + reg;
      if (row < NN) {
#pragma unroll
        for (int ct = 0; ct < 8; ct++) {
          H[(size_t)row * 128 + ct * 16 + l15] = (half_t)acc[rt][ct][reg];
        }
      }
    }
  }

  float s_lo[4], s_hi[4], d_lo[4], d_hi[4];
#pragma unroll
  for (int h = 0; h < 4; h++) {
    s_lo[h] = atts[h * 32 + l15];
    s_hi[h] = atts[h * 32 + 16 + l15];
    d_lo[h] = attd[h * 32 + l15];
    d_hi[h] = attd[h * 32 + 16 + l15];
  }
#pragma unroll
  for (int rt = 0; rt < 2; rt++) {
    float ps[4][4], pd[4][4];
#pragma unroll
    for (int reg = 0; reg < 4; reg++)
#pragma unroll
      for (int h = 0; h < 4; h++) {
        ps[reg][h] = acc[rt][2 * h][reg] * s_lo[h] + acc[rt][2 * h + 1][reg] * s_hi[h];
        pd[reg][h] = acc[rt][2 * h][reg] * d_lo[h] + acc[rt][2 * h + 1][reg] * d_hi[h];
      }
#pragma unroll
    for (int m = 1; m < 16; m <<= 1) {
#pragma unroll
      for (int reg = 0; reg < 4; reg++)
#pragma unroll
        for (int h = 0; h < 4; h++) {
          ps[reg][h] += __shfl_xor(ps[reg][h], m, 64);
          pd[reg][h] += __shfl_xor(pd[reg][h], m, 64);
        }
    }
    float vs = 0.f, vd = 0.f;
#pragma unroll
    for (int reg = 0; reg < 4; reg++)
#pragma unroll
      for (int h = 0; h < 4; h++) {
        if (l15 == reg * 4 + h) { vs = ps[reg][h]; vd = pd[reg][h]; }
      }
    int row = rb + wave * 32 + rt * 16 + quad * 4 + (l15 >> 2);
    int h = l15 & 3;
    if (row < NN) {
      asrc[row * 4 + h] = vs;
      adst[row * 4 + h] = vd;
    }
  }
}

// ============================ bscan: reduce partials + dual scan ============================
__global__ __launch_bounds__(256) void k_bscan(const int* __restrict__ bh, int* __restrict__ bcnt,
                                               int* __restrict__ ebase, int* __restrict__ abase,
                                               int* __restrict__ bcur, int* __restrict__ offs) {
  __shared__ int sh[256];
  int t = threadIdx.x;
  int i0 = 2 * t, i1 = 2 * t + 1;
  int ve0 = 0, ve1 = 0;
  if (i0 < NBK) {
    const int4* p = (const int4*)(bh + (size_t)i0 * NBH2);
#pragma unroll
    for (int j = 0; j < NBH2 / 4; j++) { int4 v = p[j]; ve0 += v.x + v.y + v.z + v.w; }
  }
  if (i1 < NBK) {
    const int4* p = (const int4*)(bh + (size_t)i1 * NBH2);
#pragma unroll
    for (int j = 0; j < NBH2 / 4; j++) { int4 v = p[j]; ve1 += v.x + v.y + v.z + v.w; }
  }
  if (i0 < NBK) bcnt[i0] = ve0;
  if (i1 < NBK) bcnt[i1] = ve1;
  int nl0 = (i0 < NBK) ? min(BSZ, NN - (i0 << BSH)) : 0;
  int nl1 = (i1 < NBK) ? min(BSZ, NN - (i1 << BSH)) : 0;
  {
    int s2 = ve0 + ve1;
    int x = s2;
    sh[t] = x;
    for (int off = 1; off < 256; off <<= 1) {
      __syncthreads();
      int y = (t >= off) ? sh[t - off] : 0;
      __syncthreads();
      x += y;
      sh[t] = x;
    }
    int ex = x - s2;
    if (i0 < NBK) { ebase[i0] = ex; bcur[i0] = ex; }
    if (i1 < NBK) { ebase[i1] = ex + ve0; bcur[i1] = ex + ve0; }
  }
  __syncthreads();
  {
    int a0 = ve0 + nl0, a1 = ve1 + nl1;
    int s2 = a0 + a1;
    int x = s2;
    sh[t] = x;
    for (int off = 1; off < 256; off <<= 1) {
      __syncthreads();
      int y = (t >= off) ? sh[t - off] : 0;
      __syncthreads();
      x += y;
      sh[t] = x;
    }
    int ex = x - s2;
    if (i0 < NBK) abase[i0] = ex;
    if (i1 < NBK) abase[i1] = ex + a0;
  }
  if (t == 0) offs[NN] = NT;
}

// ============================ pass A: bin edges by bucket ============================
__global__ __launch_bounds__(256) void k_binA(const int* __restrict__ src, const int* __restrict__ dst,
                                              int* __restrict__ bcur, unsigned int* __restrict__ bpk) {
  __shared__ int hist[NBK];
  __shared__ int hscan[NBK];
  __shared__ int gbase[NBK];
  __shared__ int cnt[NBK];
  __shared__ int ssc[256];
  __shared__ unsigned int staged[TA];
  int t = threadIdx.x;
  int e0 = blockIdx.x * TA;
  for (int i = t; i < NBK; i += 256) { hist[i] = 0; cnt[i] = 0; }
  __syncthreads();
#pragma unroll
  for (int i = 0; i < TA / 256; i++) {
    int e = e0 + t + i * 256;
    if (e < NE) atomicAdd(&hist[dst[e] >> BSH], 1);
  }
  __syncthreads();
  {
    int v0 = (2 * t < NBK) ? hist[2 * t] : 0;
    int v1 = (2 * t + 1 < NBK) ? hist[2 * t + 1] : 0;
    int x = v0 + v1;
    ssc[t] = x;
    for (int off = 1; off < 256; off <<= 1) {
      __syncthreads();
      int y = (t >= off) ? ssc[t - off] : 0;
      __syncthreads();
      x += y;
      ssc[t] = x;
    }
    int ex = x - (v0 + v1);
    if (2 * t < NBK) { hscan[2 * t] = ex; if (v0 > 0) gbase[2 * t] = atomicAdd(&bcur[2 * t], v0); }
    if (2 * t + 1 < NBK) { hscan[2 * t + 1] = ex + v0; if (v1 > 0) gbase[2 * t + 1] = atomicAdd(&bcur[2 * t + 1], v1); }
  }
  __syncthreads();
#pragma unroll
  for (int i = 0; i < TA / 256; i++) {
    int e = e0 + t + i * 256;
    if (e < NE) {
      int d = dst[e];
      int b = d >> BSH;
      int pos = hscan[b] + atomicAdd(&cnt[b], 1);
      staged[pos] = ((unsigned int)src[e] << BSH) | (unsigned int)(d & (BSZ - 1));
    }
  }
  __syncthreads();
  int wave = t >> 6, lane = t & 63;
  for (int b = wave; b < NBK; b += 4) {
    int c = hist[b];
    if (c > 0) {
      int lo = hscan[b], gb = gbase[b];
      for (int j = lane; j < c; j += 64) bpk[gb + j] = staged[lo + j];
    }
  }
}

// ============================ pass B: sort bucket by dst, add self-loops, emit offs + adj ==========
__global__ __launch_bounds__(256) void k_binB(const unsigned int* __restrict__ bpk,
                                              const int* __restrict__ bcnt,
                                              const int* __restrict__ ebase,
                                              const int* __restrict__ abase,
                                              int* __restrict__ offs, int* __restrict__ adj) {
  __shared__ int lhist[BSZ];
  __shared__ int lscan[BSZ];
  __shared__ int lcur[BSZ];
  __shared__ unsigned int staged[CAPB];
  int b = blockIdx.x;
  int t = threadIdx.x;
  int nbeg = b << BSH;
  int nloc = min(BSZ, NN - nbeg);
  int ebeg = ebase[b];
  int ecnt = bcnt[b];
  int aeg = abase[b];
  int total = ecnt + nloc;
  lhist[t] = (t < nloc) ? 1 : 0;   // self-loop occupies slot 0 of each node's segment
  lcur[t] = 1;
  __syncthreads();
  for (int i = t; i < ecnt; i += 256) atomicAdd(&lhist[bpk[ebeg + i] & (BSZ - 1)], 1);
  __syncthreads();
  {
    int v = lhist[t];
    int x = v;
    lscan[t] = x;
    for (int off = 1; off < 256; off <<= 1) {
      __syncthreads();
      int y = (t >= off) ? lscan[t - off] : 0;
      __syncthreads();
      x += y;
      lscan[t] = x;
    }
    __syncthreads();
    lscan[t] = x - v;
  }
  __syncthreads();
  if (t < nloc) {
    offs[nbeg + t] = aeg + lscan[t];
    staged[lscan[t]] = (unsigned int)(nbeg + t);   // self-loop: src = node itself
  }
  __syncthreads();
  for (int i = t; i < ecnt; i += 256) {
    unsigned int v = bpk[ebeg + i];
    int dl = v & (BSZ - 1);
    int idx = lscan[dl] + atomicAdd(&lcur[dl], 1);
    unsigned int s = v >> BSH;
    if (idx < CAPB) staged[idx] = s;
    else adj[aeg + idx] = (int)s;  // statistically never
  }
  __syncthreads();
  int lim = min(total, CAPB);
  for (int i = t; i < lim; i += 256) adj[aeg + i] = (int)staged[i];
}

// ============================ fused aggregation (w computed inline) ============================
// one wave per dst node; 16 lanes x half8 per row; 4 edges in flight; 1-deep software pipeline
// on (adj -> asrc) so next edge's index+logit load overlaps current edge's exp+H-row+FMA.
__global__ __launch_bounds__(256) void k_agg(const half_t* __restrict__ H, const int* __restrict__ offs,
                                             const int* __restrict__ adj, const float* __restrict__ asrc,
                                             const float* __restrict__ adst, const float* __restrict__ bias,
                                             half_t* __restrict__ out) {
  int n = blockIdx.x * 4 + (threadIdx.x >> 6);
  if (n >= NN) return;
  int lane = threadIdx.x & 63;
  int l15 = lane & 15, g = lane >> 4;
  int head = l15 >> 2;
  float ad = adst[(size_t)n * 4 + head];
  float acc[8] = {0.f, 0.f, 0.f, 0.f, 0.f, 0.f, 0.f, 0.f};
  float wsum = 0.f;
  int beg = offs[n], end = offs[n + 1];
  int i = beg + g;
  int s = 0;
  float a = 0.f;
  if (i < end) {
    s = adj[i];
    a = asrc[(size_t)s * 4 + head];
  }
  while (i < end) {
    int inext = i + 4;
    int sn = 0;
    float an = 0.f;
    if (inext < end) {             // prefetch next edge's index + logit
      sn = adj[inext];
      an = asrc[(size_t)sn * 4 + head];
    }
    float ev = a + ad;
    ev = (ev > 0.f) ? ev : 0.2f * ev;
    float w = __expf(ev);
    f16x8 hv = *(const f16x8*)(H + (size_t)s * 128 + l15 * 8);
    wsum += w;
#pragma unroll
    for (int j = 0; j < 8; j++) acc[j] += w * (float)hv[j];
    s = sn; a = an; i = inext;
  }
#pragma unroll
  for (int m = 16; m < 64; m <<= 1) {
    wsum += __shfl_xor(wsum, m, 64);
#pragma unroll
    for (int j = 0; j < 8; j++) acc[j] += __shfl_xor(acc[j], m, 64);
  }
  float scale = 1.0f / (wsum + 1e-16f);
  float o0 = acc[0], o1 = acc[1];
  if (g == 1) { o0 = acc[2]; o1 = acc[3]; }
  if (g == 2) { o0 = acc[4]; o1 = acc[5]; }
  if (g == 3) { o0 = acc[6]; o1 = acc[7]; }
  int ch = l15 * 8 + g * 2;
  o0 = fmaxf(o0 * scale + bias[ch], 0.f);
  o1 = fmaxf(o1 * scale + bias[ch + 1], 0.f);
  f16x2 o;
  o[0] = (half_t)o0;
  o[1] = (half_t)o1;
  *(f16x2*)(out + (size_t)n * 128 + ch) = o;
}

// ============================ MFMA GEMM (half input, pre-transposed W) + logits ============================
__global__ __launch_bounds__(256) void k_gemm_att(const half_t* __restrict__ X, const half_t* __restrict__ WT,
                                                  const float* __restrict__ atts, const float* __restrict__ attd,
                                                  half_t* __restrict__ H, float* __restrict__ asrc,
                                                  float* __restrict__ adst) {
  __shared__ __align__(16) half_t Xt[128 * 40];
  __shared__ __align__(16) half_t Wt[128 * 40];
  int t = threadIdx.x;
  int wave = t >> 6, lane = t & 63;
  int l15 = lane & 15, quad = lane >> 4;
  int rb = blockIdx.x * 128;

  f32x4 acc[2][8];
#pragma unroll
  for (int rt = 0; rt < 2; rt++)
#pragma unroll
    for (int ct = 0; ct < 8; ct++) acc[rt][ct] = (f32x4){0.f, 0.f, 0.f, 0.f};

  for (int k0 = 0; k0 < 128; k0 += 32) {
    __syncthreads();
#pragma unroll
    for (int i = 0; i < 2; i++) {
      int lin = i * 256 + t;
      int row = lin >> 2;
      int c8 = (lin & 3) * 8;
      f16x8 hv = (f16x8)(half_t)0;
      int gr = rb + row;
      if (gr < NN) hv = *(const f16x8*)(X + (size_t)gr * 128 + k0 + c8);
      *(f16x8*)(Xt + row * 40 + c8) = hv;
    }
#pragma unroll
    for (int i = 0; i < 2; i++) {
      int lin = i * 256 + t;
      int row = lin >> 2;
      int c8 = (lin & 3) * 8;
      *(f16x8*)(Wt + row * 40 + c8) = *(const f16x8*)(WT + (size_t)row * 128 + k0 + c8);
    }
    __syncthreads();

    f16x8 a0 = *(const f16x8*)(Xt + (wave * 32 + l15) * 40 + quad * 8);
    f16x8 a1 = *(const f16x8*)(Xt + (wave * 32 + 16 + l15) * 40 + quad * 8);
#pragma unroll
    for (int ct = 0; ct < 8; ct++) {
      f16x8 b = *(const f16x8*)(Wt + (ct * 16 + l15) * 40 + quad * 8);
      acc[0][ct] = __builtin_amdgcn_mfma_f32_16x16x32_f16(a0, b, acc[0][ct], 0, 0, 0);
      acc[1][ct] = __builtin_amdgcn_mfma_f32_16x16x32_f16(a1, b, acc[1][ct], 0, 0, 0);
    }
  }

#pragma unroll
  for (int rt = 0; rt < 2; rt++) {
    int rbase = rb + wave * 32 + rt * 16 + quad * 4;
#pragma unroll
    for (int reg = 0; reg < 4; reg++) {
      int row = rbase + reg;
      if (row < NN) {
#pragma unroll
        for (int ct = 0; ct < 8; ct++) {
          H[(size_t)row * 128 + ct * 16 + l15] = (half_t)acc[rt][ct][reg];
        }
      }
    }
  }

  float s_lo[4], s_hi[4], d_lo[4], d_hi[4];
#pragma unroll
  for (int h = 0; h < 4; h++) {
    s_lo[h] = atts[h * 32 + l15];
    s_hi[h] = atts[h * 32 + 16 + l15];
    d_lo[h] = attd[h * 32 + l15];
    d_hi[h] = attd[h * 32 + 16 + l15];
  }
#pragma unroll
  for (int rt = 0; rt < 2; rt++) {
    float ps[4][4], pd[4][4];
#pragma unroll
    for (int reg = 0; reg < 4; reg++)
#pragma unroll
      for (int h = 0; h < 4; h++) {
        ps[reg][h] = acc[rt][2 * h][reg] * s_lo[h] + acc[rt][2 * h + 1][reg] * s_hi[h];
        pd[reg][h] = acc[rt][2 * h][reg] * d_lo[h] + acc[rt][2 * h + 1][reg] * d_hi[h];
      }
#pragma unroll
    for (int m = 1; m < 16; m <<= 1) {
#pragma unroll
      for (int reg = 0; reg < 4; reg++)
#pragma unroll
        for (int h = 0; h < 4; h++) {
          ps[reg][h] += __shfl_xor(ps[reg][h], m, 64);
          pd[reg][h] += __shfl_xor(pd[reg][h], m, 64);
        }
    }
    float vs = 0.f, vd = 0.f;
#pragma unroll
    for (int reg = 0; reg < 4; reg++)
#pragma unroll
      for (int h = 0; h < 4; h++) {
        if (l15 == reg * 4 + h) { vs = ps[reg][h]; vd = pd[reg][h]; }
      }
    int row = rb + wave * 32 + rt * 16 + quad * 4 + (l15 >> 2);
    int h = l15 & 3;
    if (row < NN) {
      asrc[row * 4 + h] = vs;
      adst[row * 4 + h] = vd;
    }
  }
}

// ============================ classifier (MFMA, Wc pre-transposed, N padded to 48) ============================
__global__ __launch_bounds__(256) void k_classifier(const half_t* __restrict__ Hf, const half_t* __restrict__ WTc,
                                                    const float* __restrict__ bc, float* __restrict__ out) {
  __shared__ __align__(16) half_t Xt[128 * 40];
  __shared__ __align__(16) half_t Wt[48 * 40];
  int t = threadIdx.x;
  int wave = t >> 6, lane = t & 63;
  int l15 = lane & 15, quad = lane >> 4;
  int rb = blockIdx.x * 128;

  f32x4 acc[2][3];
#pragma unroll
  for (int rt = 0; rt < 2; rt++)
#pragma unroll
    for (int ct = 0; ct < 3; ct++) acc[rt][ct] = (f32x4){0.f, 0.f, 0.f, 0.f};

  for (int k0 = 0; k0 < 128; k0 += 32) {
    __syncthreads();
#pragma unroll
    for (int i = 0; i < 2; i++) {
      int lin = i * 256 + t;
      int row = lin >> 2;
      int c8 = (lin & 3) * 8;
      f16x8 hv = (f16x8)(half_t)0;
      int gr = rb + row;
      if (gr < NN) hv = *(const f16x8*)(Hf + (size_t)gr * 128 + k0 + c8);
      *(f16x8*)(Xt + row * 40 + c8) = hv;
    }
    if (t < 192) {
      int row = t >> 2;
      int c8 = (t & 3) * 8;
      *(f16x8*)(Wt + row * 40 + c8) = *(const f16x8*)(WTc + (size_t)row * 128 + k0 + c8);
    }
    __syncthreads();

    f16x8 a0 = *(const f16x8*)(Xt + (wave * 32 + l15) * 40 + quad * 8);
    f16x8 a1 = *(const f16x8*)(Xt + (wave * 32 + 16 + l15) * 40 + quad * 8);
#pragma unroll
    for (int ct = 0; ct < 3; ct++) {
      f16x8 b = *(const f16x8*)(Wt + (ct * 16 + l15) * 40 + quad * 8);
      acc[0][ct] = __builtin_amdgcn_mfma_f32_16x16x32_f16(a0, b, acc[0][ct], 0, 0, 0);
      acc[1][ct] = __builtin_amdgcn_mfma_f32_16x16x32_f16(a1, b, acc[1][ct], 0, 0, 0);
    }
  }

#pragma unroll
  for (int rt = 0; rt < 2; rt++) {
#pragma unroll
    for (int ct = 0; ct < 3; ct++) {
      int col = ct * 16 + l15;
      if (col < 40) {
        float bv = bc[col];
#pragma unroll
        for (int reg = 0; reg < 4; reg++) {
          int row = rb + wave * 32 + rt * 16 + quad * 4 + reg;
          if (row < NN) out[(size_t)row * 40 + col] = acc[rt][ct][reg] + bv;
        }
      }
    }
  }
}

// ============================ launch ============================

extern "C" void kernel_launch(void* const* d_in, const int* in_sizes, int n_in,
                              void* d_out, int out_size, void* d_ws, size_t ws_size,
                              hipStream_t stream) {
  const float* x   = (const float*)d_in[0];
  const int*   ei  = (const int*)d_in[1];
  const float* W1  = (const float*)d_in[2];
  const float* as1 = (const float*)d_in[3];
  const float* ad1 = (const float*)d_in[4];
  const float* b1  = (const float*)d_in[5];
  const float* W2  = (const float*)d_in[6];
  const float* as2 = (const float*)d_in[7];
  const float* ad2 = (const float*)d_in[8];
  const float* b2  = (const float*)d_in[9];
  const float* Wc  = (const float*)d_in[10];
  const float* bc  = (const float*)d_in[11];
  float* out = (float*)d_out;

  const int* esrc = ei;
  const int* edst = ei + NE;

  char* w = (char*)d_ws;
  auto alloc = [&](size_t bytes) {
    void* p = (void*)w;
    w += (bytes + 255) & ~(size_t)255;
    return p;
  };
  half_t* A   = (half_t*)alloc(sizeof(half_t) * (size_t)NN * 128);  // gather target
  half_t* B   = (half_t*)alloc(sizeof(half_t) * (size_t)NN * 128);  // layer output
  float* asrc = (float*)alloc(sizeof(float) * (size_t)NN * 4);
  float* adst = (float*)alloc(sizeof(float) * (size_t)NN * 4);
  int* offs   = (int*)alloc(sizeof(int) * (NN + 1));
  unsigned int* bpk = (unsigned int*)alloc(sizeof(unsigned int) * NE);
  int* adj    = (int*)alloc(sizeof(int) * NT);
  half_t* WT2 = (half_t*)alloc(sizeof(half_t) * 128 * 128);
  half_t* WTc = (half_t*)alloc(sizeof(half_t) * 48 * 128);
  int* bh     = (int*)alloc(sizeof(int) * NBK * NBH2);
  int* bcnt   = (int*)alloc(sizeof(int) * NBK);
  int* ebase  = (int*)alloc(sizeof(int) * NBK);
  int* abase  = (int*)alloc(sizeof(int) * NBK);
  int* bcur   = (int*)alloc(sizeof(int) * NBK);

  // ---- fused front: gemm1 + weight transposes + partial histograms ----
  k_front<<<NBG + NPREP + NBH2, 256, 0, stream>>>(x, W1, as1, ad1, A, asrc, adst,
                                                  W2, Wc, WT2, WTc, edst, bh);
  // ---- CSR build ----
  k_bscan<<<1, 256, 0, stream>>>(bh, bcnt, ebase, abase, bcur, offs);
  k_binA<<<NBA, 256, 0, stream>>>(esrc, edst, bcur, bpk);
  k_binB<<<NBK, 256, 0, stream>>>(bpk, bcnt, ebase, abase, offs, adj);

  // ---- layer 1 aggregate (w inline) ----
  k_agg<<<(NN + 3) / 4, 256, 0, stream>>>(A, offs, adj, asrc, adst, b1, B);

  // ---- layer 2 ----
  k_gemm_att<<<(NN + 127) / 128, 256, 0, stream>>>(B, WT2, as2, ad2, A, asrc, adst);
  k_agg<<<(NN + 3) / 4, 256, 0, stream>>>(A, offs, adj, asrc, adst, b2, B);

  // ---- classifier ----
  k_classifier<<<(NN + 127) / 128, 256, 0, stream>>>(B, WTc, bc, out);
}

// Round 9
// 414.663 us; speedup vs baseline: 1.1698x; 1.0675x over previous
//
#include <hip/hip_runtime.h>

#define NN   100000
#define NE   1600000
#define BSH  9            // 512 nodes per bucket
#define BSZ  512
#define NBK  196          // ceil(NN/512)
#define TA   8192         // edges per binA block
#define NBA  196          // ceil(NE/TA)
#define CAP  8704         // per-bucket capacity in bpk (avg 8163 + 6 sigma)
#define CAP2 9216         // per-bucket capacity in adj (CAP + BSZ self-loops)
#define NBG  782          // gemm blocks in k_front
#define NPREP 6           // W2 (4 tiles) + Wc (2 tiles)

typedef _Float16 half_t;
typedef __attribute__((ext_vector_type(2))) _Float16 f16x2;
typedef __attribute__((ext_vector_type(4))) _Float16 f16x4;
typedef __attribute__((ext_vector_type(8))) _Float16 f16x8;
typedef __attribute__((ext_vector_type(4))) float    f32x4;

// ============================ K1: fused front ============================
// blocks [0,782): gemm1 (fp32 X @ fp32 W1 -> H fp16 + logits)
// blocks [782,788): transpose W2/Wc to fp16 [n][k]
// block 788: init bcur[b] = b*CAP
__global__ __launch_bounds__(256) void k_front(const float* __restrict__ X, const float* __restrict__ W1,
                                               const float* __restrict__ atts, const float* __restrict__ attd,
                                               half_t* __restrict__ H, float* __restrict__ asrc,
                                               float* __restrict__ adst,
                                               const float* __restrict__ W2, const float* __restrict__ Wc,
                                               half_t* __restrict__ WT2, half_t* __restrict__ WTc,
                                               int* __restrict__ bcur) {
  __shared__ __align__(16) char smem[20480];
  int t = threadIdx.x;
  int bid = blockIdx.x;

  if (bid == NBG + NPREP) {
    if (t < NBK) bcur[t] = t * CAP;
    return;
  }

  if (bid >= NBG) {
    // ---- weight transpose role ----
    int b = bid - NBG;
    float (*tile)[65] = (float(*)[65])smem;  // 64x65 fp32 = 16.6KB
    const float* W;
    half_t* WT;
    int k0, n0, N, NTr;
    if (b < 4) { W = W2; WT = WT2; k0 = (b >> 1) * 64; n0 = (b & 1) * 64; N = 128; NTr = 128; }
    else       { int bb = b - 4; W = Wc; WT = WTc; k0 = bb * 64; n0 = 0; N = 40; NTr = 48; }
    int col = t & 63, r4 = t >> 6;
#pragma unroll
    for (int i = 0; i < 16; i++) {
      int row = r4 * 16 + i;                       // k-local
      float v = 0.f;
      if (n0 + col < N) v = W[(size_t)(k0 + row) * N + n0 + col];
      tile[row][col] = v;
    }
    __syncthreads();
#pragma unroll
    for (int i = 0; i < 16; i++) {
      int nrow = r4 * 16 + i;                      // n-local
      if (n0 + nrow < NTr) WT[(size_t)(n0 + nrow) * 128 + k0 + col] = (half_t)tile[col][nrow];
    }
    return;
  }

  // ---- gemm1 role ----
  half_t* Xt = (half_t*)smem;          // [128][40]
  half_t* Wt = Xt + 128 * 40;          // [n][k] [128][40]
  int wave = t >> 6, lane = t & 63;
  int l15 = lane & 15, quad = lane >> 4;
  int rb = bid * 128;

  f32x4 acc[2][8];
#pragma unroll
  for (int rt = 0; rt < 2; rt++)
#pragma unroll
    for (int ct = 0; ct < 8; ct++) acc[rt][ct] = (f32x4){0.f, 0.f, 0.f, 0.f};

  for (int k0 = 0; k0 < 128; k0 += 32) {
    __syncthreads();
#pragma unroll
    for (int i = 0; i < 4; i++) {
      int lin = i * 256 + t;
      int row = lin >> 3;
      int c4 = (lin & 7) * 4;
      float4 v = make_float4(0.f, 0.f, 0.f, 0.f);
      int gr = rb + row;
      if (gr < NN) v = *(const float4*)(X + (size_t)gr * 128 + k0 + c4);
      f16x4 hv;
      hv[0] = (half_t)v.x; hv[1] = (half_t)v.y; hv[2] = (half_t)v.z; hv[3] = (half_t)v.w;
      *(f16x4*)(Xt + row * 40 + c4) = hv;
    }
#pragma unroll
    for (int i = 0; i < 4; i++) {
      int lin = i * 256 + t;
      int kr = lin >> 5;
      int n4 = (lin & 31) * 4;
      float4 v = *(const float4*)(W1 + (size_t)(k0 + kr) * 128 + n4);
      Wt[(n4 + 0) * 40 + kr] = (half_t)v.x;
      Wt[(n4 + 1) * 40 + kr] = (half_t)v.y;
      Wt[(n4 + 2) * 40 + kr] = (half_t)v.z;
      Wt[(n4 + 3) * 40 + kr] = (half_t)v.w;
    }
    __syncthreads();

    f16x8 a0 = *(const f16x8*)(Xt + (wave * 32 + l15) * 40 + quad * 8);
    f16x8 a1 = *(const f16x8*)(Xt + (wave * 32 + 16 + l15) * 40 + quad * 8);
#pragma unroll
    for (int ct = 0; ct < 8; ct++) {
      f16x8 b = *(const f16x8*)(Wt + (ct * 16 + l15) * 40 + quad * 8);
      acc[0][ct] = __builtin_amdgcn_mfma_f32_16x16x32_f16(a0, b, acc[0][ct], 0, 0, 0);
      acc[1][ct] = __builtin_amdgcn_mfma_f32_16x16x32_f16(a1, b, acc[1][ct], 0, 0, 0);
    }
  }

#pragma unroll
  for (int rt = 0; rt < 2; rt++) {
    int rbase = rb + wave * 32 + rt * 16 + quad * 4;
#pragma unroll
    for (int reg = 0; reg < 4; reg++) {
      int row = rbase + reg;
      if (row < NN) {
#pragma unroll
        for (int ct = 0; ct < 8; ct++) {
          H[(size_t)row * 128 + ct * 16 + l15] = (half_t)acc[rt][ct][reg];
        }
      }
    }
  }

  float s_lo[4], s_hi[4], d_lo[4], d_hi[4];
#pragma unroll
  for (int h = 0; h < 4; h++) {
    s_lo[h] = atts[h * 32 + l15];
    s_hi[h] = atts[h * 32 + 16 + l15];
    d_lo[h] = attd[h * 32 + l15];
    d_hi[h] = attd[h * 32 + 16 + l15];
  }
#pragma unroll
  for (int rt = 0; rt < 2; rt++) {
    float ps[4][4], pd[4][4];
#pragma unroll
    for (int reg = 0; reg < 4; reg++)
#pragma unroll
      for (int h = 0; h < 4; h++) {
        ps[reg][h] = acc[rt][2 * h][reg] * s_lo[h] + acc[rt][2 * h + 1][reg] * s_hi[h];
        pd[reg][h] = acc[rt][2 * h][reg] * d_lo[h] + acc[rt][2 * h + 1][reg] * d_hi[h];
      }
#pragma unroll
    for (int m = 1; m < 16; m <<= 1) {
#pragma unroll
      for (int reg = 0; reg < 4; reg++)
#pragma unroll
        for (int h = 0; h < 4; h++) {
          ps[reg][h] += __shfl_xor(ps[reg][h], m, 64);
          pd[reg][h] += __shfl_xor(pd[reg][h], m, 64);
        }
    }
    float vs = 0.f, vd = 0.f;
#pragma unroll
    for (int reg = 0; reg < 4; reg++)
#pragma unroll
      for (int h = 0; h < 4; h++) {
        if (l15 == reg * 4 + h) { vs = ps[reg][h]; vd = pd[reg][h]; }
      }
    int row = rb + wave * 32 + rt * 16 + quad * 4 + (l15 >> 2);
    int h = l15 & 3;
    if (row < NN) {
      asrc[row * 4 + h] = vs;
      adst[row * 4 + h] = vd;
    }
  }
}

// ============================ pass A: bin edges into padded buckets ============================
__global__ __launch_bounds__(256) void k_binA(const int* __restrict__ src, const int* __restrict__ dst,
                                              int* __restrict__ bcur, unsigned int* __restrict__ bpk) {
  __shared__ int hist[NBK];
  __shared__ int hscan[NBK];
  __shared__ int gbase[NBK];
  __shared__ int cnt[NBK];
  __shared__ int ssc[256];
  __shared__ unsigned int staged[TA];
  int t = threadIdx.x;
  int e0 = blockIdx.x * TA;
  if (t < NBK) { hist[t] = 0; cnt[t] = 0; }
  __syncthreads();
#pragma unroll
  for (int i = 0; i < TA / 256; i++) {
    int e = e0 + t + i * 256;
    if (e < NE) atomicAdd(&hist[dst[e] >> BSH], 1);
  }
  __syncthreads();
  // exclusive scan of hist (196 <= 256) + global allocation
  {
    int v = (t < NBK) ? hist[t] : 0;
    int x = v;
    ssc[t] = x;
    for (int off = 1; off < 256; off <<= 1) {
      __syncthreads();
      int y = (t >= off) ? ssc[t - off] : 0;
      __syncthreads();
      x += y;
      ssc[t] = x;
    }
    if (t < NBK) {
      hscan[t] = x - v;
      if (v > 0) gbase[t] = atomicAdd(&bcur[t], v);
    }
  }
  __syncthreads();
#pragma unroll
  for (int i = 0; i < TA / 256; i++) {
    int e = e0 + t + i * 256;
    if (e < NE) {
      int d = dst[e];
      int b = d >> BSH;
      int pos = hscan[b] + atomicAdd(&cnt[b], 1);
      staged[pos] = ((unsigned int)src[e] << BSH) | (unsigned int)(d & (BSZ - 1));
    }
  }
  __syncthreads();
  // contiguous flush: avg ~42 consecutive entries per bucket run
  int wave = t >> 6, lane = t & 63;
  for (int b = wave; b < NBK; b += 4) {
    int c = hist[b];
    if (c > 0) {
      int lo = hscan[b], gb = gbase[b];
      for (int j = lane; j < c; j += 64) bpk[gb + j] = staged[lo + j];
    }
  }
}

// ============================ pass B: sort bucket by dst, add self-loops, emit sbeg/send + adj ====
__global__ __launch_bounds__(256) void k_binB(const unsigned int* __restrict__ bpk,
                                              const int* __restrict__ bcur,
                                              int* __restrict__ sbeg, int* __restrict__ send,
                                              int* __restrict__ adj) {
  __shared__ int lhist[BSZ];
  __shared__ int lscan[BSZ];
  __shared__ int lcur[BSZ];
  __shared__ int ssc[256];
  __shared__ unsigned int staged[CAP2];
  int b = blockIdx.x;
  int t = threadIdx.x;
  int nbeg = b << BSH;
  int nloc = min(BSZ, NN - nbeg);
  int ebeg = b * CAP;
  int ecnt = bcur[b] - ebeg;
  int adjb = b * CAP2;
  int total = ecnt + nloc;
  lhist[2 * t] = (2 * t < nloc) ? 1 : 0;       // self-loop occupies slot 0 of each node's segment
  lhist[2 * t + 1] = (2 * t + 1 < nloc) ? 1 : 0;
  lcur[2 * t] = 1;
  lcur[2 * t + 1] = 1;
  __syncthreads();
  for (int i = t; i < ecnt; i += 256) atomicAdd(&lhist[bpk[ebeg + i] & (BSZ - 1)], 1);
  __syncthreads();
  // exclusive scan of 512 with 256 threads
  {
    int v0 = lhist[2 * t], v1 = lhist[2 * t + 1];
    int s2 = v0 + v1;
    int x = s2;
    ssc[t] = x;
    for (int off = 1; off < 256; off <<= 1) {
      __syncthreads();
      int y = (t >= off) ? ssc[t - off] : 0;
      __syncthreads();
      x += y;
      ssc[t] = x;
    }
    int ex = x - s2;
    lscan[2 * t] = ex;
    lscan[2 * t + 1] = ex + v0;
  }
  __syncthreads();
  // per-node CSR bounds + self-loop records
#pragma unroll
  for (int u = 0; u < 2; u++) {
    int i = t + u * 256;
    if (i < nloc) {
      int bg = adjb + lscan[i];
      sbeg[nbeg + i] = bg;
      send[nbeg + i] = bg + lhist[i];
      staged[lscan[i]] = (unsigned int)(nbeg + i);   // self-loop: src = node itself
    }
  }
  __syncthreads();
  // scatter edges (slots after the self-loop)
  for (int i = t; i < ecnt; i += 256) {
    unsigned int v = bpk[ebeg + i];
    int dl = v & (BSZ - 1);
    int idx = lscan[dl] + atomicAdd(&lcur[dl], 1);
    staged[idx] = v >> BSH;
  }
  __syncthreads();
  // contiguous stream-out
  for (int i = t; i < total; i += 256) adj[adjb + i] = (int)staged[i];
}

// ============================ fused aggregation (w computed inline) ============================
__global__ __launch_bounds__(256) void k_agg(const half_t* __restrict__ H, const int* __restrict__ sbeg,
                                             const int* __restrict__ send, const int* __restrict__ adj,
                                             const float* __restrict__ asrc, const float* __restrict__ adst,
                                             const float* __restrict__ bias, half_t* __restrict__ out) {
  int n = blockIdx.x * 4 + (threadIdx.x >> 6);
  if (n >= NN) return;
  int lane = threadIdx.x & 63;
  int l15 = lane & 15, g = lane >> 4;
  int head = l15 >> 2;
  float ad = adst[(size_t)n * 4 + head];
  float acc[8] = {0.f, 0.f, 0.f, 0.f, 0.f, 0.f, 0.f, 0.f};
  float wsum = 0.f;
  int beg = sbeg[n], end = send[n];
  int i = beg + g;
  int s = 0;
  float a = 0.f;
  if (i < end) {
    s = adj[i];
    a = asrc[(size_t)s * 4 + head];
  }
  while (i < end) {
    int inext = i + 4;
    int sn = 0;
    float an = 0.f;
    if (inext < end) {             // prefetch next edge's index + logit
      sn = adj[inext];
      an = asrc[(size_t)sn * 4 + head];
    }
    float ev = a + ad;
    ev = (ev > 0.f) ? ev : 0.2f * ev;
    float w = __expf(ev);
    f16x8 hv = *(const f16x8*)(H + (size_t)s * 128 + l15 * 8);
    wsum += w;
#pragma unroll
    for (int j = 0; j < 8; j++) acc[j] += w * (float)hv[j];
    s = sn; a = an; i = inext;
  }
#pragma unroll
  for (int m = 16; m < 64; m <<= 1) {
    wsum += __shfl_xor(wsum, m, 64);
#pragma unroll
    for (int j = 0; j < 8; j++) acc[j] += __shfl_xor(acc[j], m, 64);
  }
  float scale = 1.0f / (wsum + 1e-16f);
  float o0 = acc[0], o1 = acc[1];
  if (g == 1) { o0 = acc[2]; o1 = acc[3]; }
  if (g == 2) { o0 = acc[4]; o1 = acc[5]; }
  if (g == 3) { o0 = acc[6]; o1 = acc[7]; }
  int ch = l15 * 8 + g * 2;
  o0 = fmaxf(o0 * scale + bias[ch], 0.f);
  o1 = fmaxf(o1 * scale + bias[ch + 1], 0.f);
  f16x2 o;
  o[0] = (half_t)o0;
  o[1] = (half_t)o1;
  *(f16x2*)(out + (size_t)n * 128 + ch) = o;
}

// ============================ MFMA GEMM (half input, pre-transposed W) + logits ============================
__global__ __launch_bounds__(256) void k_gemm_att(const half_t* __restrict__ X, const half_t* __restrict__ WT,
                                                  const float* __restrict__ atts, const float* __restrict__ attd,
                                                  half_t* __restrict__ H, float* __restrict__ asrc,
                                                  float* __restrict__ adst) {
  __shared__ __align__(16) half_t Xt[128 * 40];
  __shared__ __align__(16) half_t Wt[128 * 40];
  int t = threadIdx.x;
  int wave = t >> 6, lane = t & 63;
  int l15 = lane & 15, quad = lane >> 4;
  int rb = blockIdx.x * 128;

  f32x4 acc[2][8];
#pragma unroll
  for (int rt = 0; rt < 2; rt++)
#pragma unroll
    for (int ct = 0; ct < 8; ct++) acc[rt][ct] = (f32x4){0.f, 0.f, 0.f, 0.f};

  for (int k0 = 0; k0 < 128; k0 += 32) {
    __syncthreads();
#pragma unroll
    for (int i = 0; i < 2; i++) {
      int lin = i * 256 + t;
      int row = lin >> 2;
      int c8 = (lin & 3) * 8;
      f16x8 hv = (f16x8)(half_t)0;
      int gr = rb + row;
      if (gr < NN) hv = *(const f16x8*)(X + (size_t)gr * 128 + k0 + c8);
      *(f16x8*)(Xt + row * 40 + c8) = hv;
    }
#pragma unroll
    for (int i = 0; i < 2; i++) {
      int lin = i * 256 + t;
      int row = lin >> 2;
      int c8 = (lin & 3) * 8;
      *(f16x8*)(Wt + row * 40 + c8) = *(const f16x8*)(WT + (size_t)row * 128 + k0 + c8);
    }
    __syncthreads();

    f16x8 a0 = *(const f16x8*)(Xt + (wave * 32 + l15) * 40 + quad * 8);
    f16x8 a1 = *(const f16x8*)(Xt + (wave * 32 + 16 + l15) * 40 + quad * 8);
#pragma unroll
    for (int ct = 0; ct < 8; ct++) {
      f16x8 b = *(const f16x8*)(Wt + (ct * 16 + l15) * 40 + quad * 8);
      acc[0][ct] = __builtin_amdgcn_mfma_f32_16x16x32_f16(a0, b, acc[0][ct], 0, 0, 0);
      acc[1][ct] = __builtin_amdgcn_mfma_f32_16x16x32_f16(a1, b, acc[1][ct], 0, 0, 0);
    }
  }

#pragma unroll
  for (int rt = 0; rt < 2; rt++) {
    int rbase = rb + wave * 32 + rt * 16 + quad * 4;
#pragma unroll
    for (int reg = 0; reg < 4; reg++) {
      int row = rbase + reg;
      if (row < NN) {
#pragma unroll
        for (int ct = 0; ct < 8; ct++) {
          H[(size_t)row * 128 + ct * 16 + l15] = (half_t)acc[rt][ct][reg];
        }
      }
    }
  }

  float s_lo[4], s_hi[4], d_lo[4], d_hi[4];
#pragma unroll
  for (int h = 0; h < 4; h++) {
    s_lo[h] = atts[h * 32 + l15];
    s_hi[h] = atts[h * 32 + 16 + l15];
    d_lo[h] = attd[h * 32 + l15];
    d_hi[h] = attd[h * 32 + 16 + l15];
  }
#pragma unroll
  for (int rt = 0; rt < 2; rt++) {
    float ps[4][4], pd[4][4];
#pragma unroll
    for (int reg = 0; reg < 4; reg++)
#pragma unroll
      for (int h = 0; h < 4; h++) {
        ps[reg][h] = acc[rt][2 * h][reg] * s_lo[h] + acc[rt][2 * h + 1][reg] * s_hi[h];
        pd[reg][h] = acc[rt][2 * h][reg] * d_lo[h] + acc[rt][2 * h + 1][reg] * d_hi[h];
      }
#pragma unroll
    for (int m = 1; m < 16; m <<= 1) {
#pragma unroll
      for (int reg = 0; reg < 4; reg++)
#pragma unroll
        for (int h = 0; h < 4; h++) {
          ps[reg][h] += __shfl_xor(ps[reg][h], m, 64);
          pd[reg][h] += __shfl_xor(pd[reg][h], m, 64);
        }
    }
    float vs = 0.f, vd = 0.f;
#pragma unroll
    for (int reg = 0; reg < 4; reg++)
#pragma unroll
      for (int h = 0; h < 4; h++) {
        if (l15 == reg * 4 + h) { vs = ps[reg][h]; vd = pd[reg][h]; }
      }
    int row = rb + wave * 32 + rt * 16 + quad * 4 + (l15 >> 2);
    int h = l15 & 3;
    if (row < NN) {
      asrc[row * 4 + h] = vs;
      adst[row * 4 + h] = vd;
    }
  }
}

// ============================ classifier (MFMA, Wc pre-transposed, N padded to 48) ============================
__global__ __launch_bounds__(256) void k_classifier(const half_t* __restrict__ Hf, const half_t* __restrict__ WTc,
                                                    const float* __restrict__ bc, float* __restrict__ out) {
  __shared__ __align__(16) half_t Xt[128 * 40];
  __shared__ __align__(16) half_t Wt[48 * 40];
  int t = threadIdx.x;
  int wave = t >> 6, lane = t & 63;
  int l15 = lane & 15, quad = lane >> 4;
  int rb = blockIdx.x * 128;

  f32x4 acc[2][3];
#pragma unroll
  for (int rt = 0; rt < 2; rt++)
#pragma unroll
    for (int ct = 0; ct < 3; ct++) acc[rt][ct] = (f32x4){0.f, 0.f, 0.f, 0.f};

  for (int k0 = 0; k0 < 128; k0 += 32) {
    __syncthreads();
#pragma unroll
    for (int i = 0; i < 2; i++) {
      int lin = i * 256 + t;
      int row = lin >> 2;
      int c8 = (lin & 3) * 8;
      f16x8 hv = (f16x8)(half_t)0;
      int gr = rb + row;
      if (gr < NN) hv = *(const f16x8*)(Hf + (size_t)gr * 128 + k0 + c8);
      *(f16x8*)(Xt + row * 40 + c8) = hv;
    }
    if (t < 192) {
      int row = t >> 2;
      int c8 = (t & 3) * 8;
      *(f16x8*)(Wt + row * 40 + c8) = *(const f16x8*)(WTc + (size_t)row * 128 + k0 + c8);
    }
    __syncthreads();

    f16x8 a0 = *(const f16x8*)(Xt + (wave * 32 + l15) * 40 + quad * 8);
    f16x8 a1 = *(const f16x8*)(Xt + (wave * 32 + 16 + l15) * 40 + quad * 8);
#pragma unroll
    for (int ct = 0; ct < 3; ct++) {
      f16x8 b = *(const f16x8*)(Wt + (ct * 16 + l15) * 40 + quad * 8);
      acc[0][ct] = __builtin_amdgcn_mfma_f32_16x16x32_f16(a0, b, acc[0][ct], 0, 0, 0);
      acc[1][ct] = __builtin_amdgcn_mfma_f32_16x16x32_f16(a1, b, acc[1][ct], 0, 0, 0);
    }
  }

#pragma unroll
  for (int rt = 0; rt < 2; rt++) {
#pragma unroll
    for (int ct = 0; ct < 3; ct++) {
      int col = ct * 16 + l15;
      if (col < 40) {
        float bv = bc[col];
#pragma unroll
        for (int reg = 0; reg < 4; reg++) {
          int row = rb + wave * 32 + rt * 16 + quad * 4 + reg;
          if (row < NN) out[(size_t)row * 40 + col] = acc[rt][ct][reg] + bv;
        }
      }
    }
  }
}

// ============================ launch ============================

extern "C" void kernel_launch(void* const* d_in, const int* in_sizes, int n_in,
                              void* d_out, int out_size, void* d_ws, size_t ws_size,
                              hipStream_t stream) {
  const float* x   = (const float*)d_in[0];
  const int*   ei  = (const int*)d_in[1];
  const float* W1  = (const float*)d_in[2];
  const float* as1 = (const float*)d_in[3];
  const float* ad1 = (const float*)d_in[4];
  const float* b1  = (const float*)d_in[5];
  const float* W2  = (const float*)d_in[6];
  const float* as2 = (const float*)d_in[7];
  const float* ad2 = (const float*)d_in[8];
  const float* b2  = (const float*)d_in[9];
  const float* Wc  = (const float*)d_in[10];
  const float* bc  = (const float*)d_in[11];
  float* out = (float*)d_out;

  const int* esrc = ei;
  const int* edst = ei + NE;

  char* w = (char*)d_ws;
  auto alloc = [&](size_t bytes) {
    void* p = (void*)w;
    w += (bytes + 255) & ~(size_t)255;
    return p;
  };
  half_t* A   = (half_t*)alloc(sizeof(half_t) * (size_t)NN * 128);  // gather target
  half_t* B   = (half_t*)alloc(sizeof(half_t) * (size_t)NN * 128);  // layer output
  float* asrc = (float*)alloc(sizeof(float) * (size_t)NN * 4);
  float* adst = (float*)alloc(sizeof(float) * (size_t)NN * 4);
  int* sbeg   = (int*)alloc(sizeof(int) * NN);
  int* send   = (int*)alloc(sizeof(int) * NN);
  unsigned int* bpk = (unsigned int*)alloc(sizeof(unsigned int) * (size_t)NBK * CAP);
  int* adj    = (int*)alloc(sizeof(int) * (size_t)NBK * CAP2);
  half_t* WT2 = (half_t*)alloc(sizeof(half_t) * 128 * 128);
  half_t* WTc = (half_t*)alloc(sizeof(half_t) * 48 * 128);
  int* bcur   = (int*)alloc(sizeof(int) * NBK);

  // ---- fused front: gemm1 + weight transposes + bcur init ----
  k_front<<<NBG + NPREP + 1, 256, 0, stream>>>(x, W1, as1, ad1, A, asrc, adst,
                                               W2, Wc, WT2, WTc, bcur);
  // ---- CSR build (padded buckets: no histogram, no scan) ----
  k_binA<<<NBA, 256, 0, stream>>>(esrc, edst, bcur, bpk);
  k_binB<<<NBK, 256, 0, stream>>>(bpk, bcur, sbeg, send, adj);

  // ---- layer 1 aggregate ----
  k_agg<<<(NN + 3) / 4, 256, 0, stream>>>(A, sbeg, send, adj, asrc, adst, b1, B);

  // ---- layer 2 ----
  k_gemm_att<<<(NN + 127) / 128, 256, 0, stream>>>(B, WT2, as2, ad2, A, asrc, adst);
  k_agg<<<(NN + 3) / 4, 256, 0, stream>>>(A, sbeg, send, adj, asrc, adst, b2, B);

  // ---- classifier ----
  k_classifier<<<(NN + 127) / 128, 256, 0, stream>>>(B, WTc, bc, out);
}

// Round 10
// 400.798 us; speedup vs baseline: 1.2103x; 1.0346x over previous
//
#include <hip/hip_runtime.h>

#define NN   100000
#define NE   1600000
#define BSH  9            // 512 nodes per bucket
#define BSZ  512
#define NBK  196          // ceil(NN/512)
#define TA   8192         // edges per binA chunk-block
#define NBA  196          // ceil(NE/TA)
#define SCAP 96           // per-(chunk,bucket) slot capacity (mean 41.8 + 8 sigma)
#define CAP2 9216         // per-bucket capacity in adj (edges + self-loops)
#define NBG  782          // gemm blocks in k_front
#define NPREP 6           // W2 (4 tiles) + Wc (2 tiles)

typedef _Float16 half_t;
typedef __attribute__((ext_vector_type(2))) _Float16 f16x2;
typedef __attribute__((ext_vector_type(4))) _Float16 f16x4;
typedef __attribute__((ext_vector_type(8))) _Float16 f16x8;
typedef __attribute__((ext_vector_type(4))) float    f32x4;

// ============================ K1: fused front ============================
// blocks [0,782): gemm1 (fp32 X @ fp32 W1 -> H fp16 + logits)
// blocks [782,788): transpose W2/Wc to fp16 [n][k]
// blocks [788,984): binA role: bin TA edges into fixed per-(chunk,bucket) slots (no global cursor)
__global__ __launch_bounds__(256) void k_front(const float* __restrict__ X, const float* __restrict__ W1,
                                               const float* __restrict__ atts, const float* __restrict__ attd,
                                               half_t* __restrict__ H, float* __restrict__ asrc,
                                               float* __restrict__ adst,
                                               const float* __restrict__ W2, const float* __restrict__ Wc,
                                               half_t* __restrict__ WT2, half_t* __restrict__ WTc,
                                               const int* __restrict__ src, const int* __restrict__ dst,
                                               unsigned int* __restrict__ bpk, int* __restrict__ bh) {
  __shared__ __align__(16) char smem[36864];
  int t = threadIdx.x;
  int bid = blockIdx.x;

  if (bid >= NBG + NPREP) {
    // ---- binA role: fixed-slot binning ----
    int hb = bid - NBG - NPREP;               // chunk-block id [0,196)
    int* hist  = (int*)smem;                  // [196]
    int* hscan = hist + NBK;                  // [196]
    int* cnt   = hscan + NBK;                 // [196]
    int* ssc   = cnt + NBK;                   // [256]
    unsigned int* staged = (unsigned int*)(ssc + 256);  // [8192]
    int e0 = hb * TA;
    if (t < NBK) { hist[t] = 0; cnt[t] = 0; }
    __syncthreads();
#pragma unroll
    for (int i = 0; i < TA / 256; i++) {
      int e = e0 + t + i * 256;
      if (e < NE) atomicAdd(&hist[dst[e] >> BSH], 1);
    }
    __syncthreads();
    // exclusive scan of hist (196 <= 256)
    {
      int v = (t < NBK) ? hist[t] : 0;
      int x = v;
      ssc[t] = x;
      for (int off = 1; off < 256; off <<= 1) {
        __syncthreads();
        int y = (t >= off) ? ssc[t - off] : 0;
        __syncthreads();
        x += y;
        ssc[t] = x;
      }
      if (t < NBK) hscan[t] = x - v;
    }
    __syncthreads();
#pragma unroll
    for (int i = 0; i < TA / 256; i++) {
      int e = e0 + t + i * 256;
      if (e < NE) {
        int d = dst[e];
        int bk = d >> BSH;
        int pos = hscan[bk] + atomicAdd(&cnt[bk], 1);
        staged[pos] = ((unsigned int)src[e] << BSH) | (unsigned int)(d & (BSZ - 1));
      }
    }
    __syncthreads();
    // contiguous flush into fixed slots; write counts
    int wave = t >> 6, lane = t & 63;
    for (int bk = wave; bk < NBK; bk += 4) {
      int c = hist[bk];
      int cw = min(c, SCAP);
      size_t base = ((size_t)bk * NBA + hb) * SCAP;
      int lo = hscan[bk];
      for (int j = lane; j < cw; j += 64) bpk[base + j] = staged[lo + j];
      if (lane == 0) bh[bk * NBA + hb] = cw;
    }
    return;
  }

  if (bid >= NBG) {
    // ---- weight transpose role ----
    int b = bid - NBG;
    float (*tile)[65] = (float(*)[65])smem;  // 64x65 fp32 = 16.6KB
    const float* W;
    half_t* WT;
    int k0, n0, N, NTr;
    if (b < 4) { W = W2; WT = WT2; k0 = (b >> 1) * 64; n0 = (b & 1) * 64; N = 128; NTr = 128; }
    else       { int bb = b - 4; W = Wc; WT = WTc; k0 = bb * 64; n0 = 0; N = 40; NTr = 48; }
    int col = t & 63, r4 = t >> 6;
#pragma unroll
    for (int i = 0; i < 16; i++) {
      int row = r4 * 16 + i;                       // k-local
      float v = 0.f;
      if (n0 + col < N) v = W[(size_t)(k0 + row) * N + n0 + col];
      tile[row][col] = v;
    }
    __syncthreads();
#pragma unroll
    for (int i = 0; i < 16; i++) {
      int nrow = r4 * 16 + i;                      // n-local
      if (n0 + nrow < NTr) WT[(size_t)(n0 + nrow) * 128 + k0 + col] = (half_t)tile[col][nrow];
    }
    return;
  }

  // ---- gemm1 role ----
  half_t* Xt = (half_t*)smem;          // [128][40]
  half_t* Wt = Xt + 128 * 40;          // [n][k] [128][40]
  int wave = t >> 6, lane = t & 63;
  int l15 = lane & 15, quad = lane >> 4;
  int rb = bid * 128;

  f32x4 acc[2][8];
#pragma unroll
  for (int rt = 0; rt < 2; rt++)
#pragma unroll
    for (int ct = 0; ct < 8; ct++) acc[rt][ct] = (f32x4){0.f, 0.f, 0.f, 0.f};

  for (int k0 = 0; k0 < 128; k0 += 32) {
    __syncthreads();
#pragma unroll
    for (int i = 0; i < 4; i++) {
      int lin = i * 256 + t;
      int row = lin >> 3;
      int c4 = (lin & 7) * 4;
      float4 v = make_float4(0.f, 0.f, 0.f, 0.f);
      int gr = rb + row;
      if (gr < NN) v = *(const float4*)(X + (size_t)gr * 128 + k0 + c4);
      f16x4 hv;
      hv[0] = (half_t)v.x; hv[1] = (half_t)v.y; hv[2] = (half_t)v.z; hv[3] = (half_t)v.w;
      *(f16x4*)(Xt + row * 40 + c4) = hv;
    }
#pragma unroll
    for (int i = 0; i < 4; i++) {
      int lin = i * 256 + t;
      int kr = lin >> 5;
      int n4 = (lin & 31) * 4;
      float4 v = *(const float4*)(W1 + (size_t)(k0 + kr) * 128 + n4);
      Wt[(n4 + 0) * 40 + kr] = (half_t)v.x;
      Wt[(n4 + 1) * 40 + kr] = (half_t)v.y;
      Wt[(n4 + 2) * 40 + kr] = (half_t)v.z;
      Wt[(n4 + 3) * 40 + kr] = (half_t)v.w;
    }
    __syncthreads();

    f16x8 a0 = *(const f16x8*)(Xt + (wave * 32 + l15) * 40 + quad * 8);
    f16x8 a1 = *(const f16x8*)(Xt + (wave * 32 + 16 + l15) * 40 + quad * 8);
#pragma unroll
    for (int ct = 0; ct < 8; ct++) {
      f16x8 b = *(const f16x8*)(Wt + (ct * 16 + l15) * 40 + quad * 8);
      acc[0][ct] = __builtin_amdgcn_mfma_f32_16x16x32_f16(a0, b, acc[0][ct], 0, 0, 0);
      acc[1][ct] = __builtin_amdgcn_mfma_f32_16x16x32_f16(a1, b, acc[1][ct], 0, 0, 0);
    }
  }

#pragma unroll
  for (int rt = 0; rt < 2; rt++) {
    int rbase = rb + wave * 32 + rt * 16 + quad * 4;
#pragma unroll
    for (int reg = 0; reg < 4; reg++) {
      int row = rbase + reg;
      if (row < NN) {
#pragma unroll
        for (int ct = 0; ct < 8; ct++) {
          H[(size_t)row * 128 + ct * 16 + l15] = (half_t)acc[rt][ct][reg];
        }
      }
    }
  }

  float s_lo[4], s_hi[4], d_lo[4], d_hi[4];
#pragma unroll
  for (int h = 0; h < 4; h++) {
    s_lo[h] = atts[h * 32 + l15];
    s_hi[h] = atts[h * 32 + 16 + l15];
    d_lo[h] = attd[h * 32 + l15];
    d_hi[h] = attd[h * 32 + 16 + l15];
  }
#pragma unroll
  for (int rt = 0; rt < 2; rt++) {
    float ps[4][4], pd[4][4];
#pragma unroll
    for (int reg = 0; reg < 4; reg++)
#pragma unroll
      for (int h = 0; h < 4; h++) {
        ps[reg][h] = acc[rt][2 * h][reg] * s_lo[h] + acc[rt][2 * h + 1][reg] * s_hi[h];
        pd[reg][h] = acc[rt][2 * h][reg] * d_lo[h] + acc[rt][2 * h + 1][reg] * d_hi[h];
      }
#pragma unroll
    for (int m = 1; m < 16; m <<= 1) {
#pragma unroll
      for (int reg = 0; reg < 4; reg++)
#pragma unroll
        for (int h = 0; h < 4; h++) {
          ps[reg][h] += __shfl_xor(ps[reg][h], m, 64);
          pd[reg][h] += __shfl_xor(pd[reg][h], m, 64);
        }
    }
    float vs = 0.f, vd = 0.f;
#pragma unroll
    for (int reg = 0; reg < 4; reg++)
#pragma unroll
      for (int h = 0; h < 4; h++) {
        if (l15 == reg * 4 + h) { vs = ps[reg][h]; vd = pd[reg][h]; }
      }
    int row = rb + wave * 32 + rt * 16 + quad * 4 + (l15 >> 2);
    int h = l15 & 3;
    if (row < NN) {
      asrc[row * 4 + h] = vs;
      adst[row * 4 + h] = vd;
    }
  }
}

// ============================ binB: gather chunks, sort bucket by dst, emit sbeg/send + adj =======
__global__ __launch_bounds__(256) void k_binB(const unsigned int* __restrict__ bpk,
                                              const int* __restrict__ bh,
                                              int* __restrict__ sbeg, int* __restrict__ send,
                                              int* __restrict__ adj) {
  __shared__ int lhist[BSZ];
  __shared__ int lscan[BSZ];
  __shared__ int lcur[BSZ];
  __shared__ int ssc[256];
  __shared__ int carr[NBA];
  __shared__ unsigned int staged[CAP2];
  int b = blockIdx.x;
  int t = threadIdx.x;
  int nbeg = b << BSH;
  int nloc = min(BSZ, NN - nbeg);
  int adjb = b * CAP2;
  // load chunk counts
  if (t < NBA) carr[t] = bh[b * NBA + t];
  lhist[2 * t] = (2 * t < nloc) ? 1 : 0;       // self-loop occupies slot 0 of each node's segment
  lhist[2 * t + 1] = (2 * t + 1 < nloc) ? 1 : 0;
  lcur[2 * t] = 1;
  lcur[2 * t + 1] = 1;
  __syncthreads();
  int wave = t >> 6, lane = t & 63;
  // pass 1: histogram by local dst (read chunks from global)
  for (int a = wave; a < NBA; a += 4) {
    int c = carr[a];
    size_t base = ((size_t)b * NBA + a) * SCAP;
    for (int j = lane; j < c; j += 64) atomicAdd(&lhist[bpk[base + j] & (BSZ - 1)], 1);
  }
  __syncthreads();
  // exclusive scan of 512 with 256 threads
  {
    int v0 = lhist[2 * t], v1 = lhist[2 * t + 1];
    int s2 = v0 + v1;
    int x = s2;
    ssc[t] = x;
    for (int off = 1; off < 256; off <<= 1) {
      __syncthreads();
      int y = (t >= off) ? ssc[t - off] : 0;
      __syncthreads();
      x += y;
      ssc[t] = x;
    }
    int ex = x - s2;
    lscan[2 * t] = ex;
    lscan[2 * t + 1] = ex + v0;
  }
  __syncthreads();
  int total = lscan[BSZ - 1] + lhist[BSZ - 1];
  // per-node CSR bounds + self-loop records
#pragma unroll
  for (int u = 0; u < 2; u++) {
    int i = t + u * 256;
    if (i < nloc) {
      int bg = adjb + lscan[i];
      sbeg[nbeg + i] = bg;
      send[nbeg + i] = bg + lhist[i];
      staged[lscan[i]] = (unsigned int)(nbeg + i);   // self-loop: src = node itself
    }
  }
  __syncthreads();
  // pass 2: scatter edges into sorted staging (slots after the self-loop)
  for (int a = wave; a < NBA; a += 4) {
    int c = carr[a];
    size_t base = ((size_t)b * NBA + a) * SCAP;
    for (int j = lane; j < c; j += 64) {
      unsigned int v = bpk[base + j];
      int dl = v & (BSZ - 1);
      int idx = lscan[dl] + atomicAdd(&lcur[dl], 1);
      if (idx < CAP2) staged[idx] = v >> BSH;
    }
  }
  __syncthreads();
  // contiguous stream-out
  int lim = min(total, CAP2);
  for (int i = t; i < lim; i += 256) adj[adjb + i] = (int)staged[i];
}

// ============================ fused aggregation: 8 edges in flight ============================
// one wave per dst node; 8 lanes x 16ch cover one 256-B row; 8 edge-groups; 1-deep prefetch.
__global__ __launch_bounds__(256) void k_agg(const half_t* __restrict__ H, const int* __restrict__ sbeg,
                                             const int* __restrict__ send, const int* __restrict__ adj,
                                             const float* __restrict__ asrc, const float* __restrict__ adst,
                                             const float* __restrict__ bias, half_t* __restrict__ out) {
  int n = blockIdx.x * 4 + (threadIdx.x >> 6);
  if (n >= NN) return;
  int lane = threadIdx.x & 63;
  int sub = lane & 7;              // 16-channel slice [sub*16, sub*16+16)
  int g = lane >> 3;               // edge group [0,8)
  int head = sub >> 1;
  float ad = adst[(size_t)n * 4 + head];
  float acc[16];
#pragma unroll
  for (int j = 0; j < 16; j++) acc[j] = 0.f;
  float wsum = 0.f;
  int beg = sbeg[n], end = send[n];
  int i = beg + g;
  int s = 0;
  float a = 0.f;
  if (i < end) {
    s = adj[i];
    a = asrc[(size_t)s * 4 + head];
  }
  while (i < end) {
    int inext = i + 8;
    int sn = 0;
    float an = 0.f;
    if (inext < end) {             // prefetch next edge's index + logit
      sn = adj[inext];
      an = asrc[(size_t)sn * 4 + head];
    }
    float ev = a + ad;
    ev = (ev > 0.f) ? ev : 0.2f * ev;
    float w = __expf(ev);
    const f16x8* hp = (const f16x8*)(H + (size_t)s * 128 + sub * 16);
    f16x8 h0 = hp[0], h1 = hp[1];
    wsum += w;
#pragma unroll
    for (int j = 0; j < 8; j++) acc[j] += w * (float)h0[j];
#pragma unroll
    for (int j = 0; j < 8; j++) acc[8 + j] += w * (float)h1[j];
    s = sn; a = an; i = inext;
  }
  // combine the 8 edge-groups (lane bits 3..5)
#pragma unroll
  for (int m = 8; m < 64; m <<= 1) {
    wsum += __shfl_xor(wsum, m, 64);
#pragma unroll
    for (int j = 0; j < 16; j++) acc[j] += __shfl_xor(acc[j], m, 64);
  }
  float scale = 1.0f / (wsum + 1e-16f);
  // lane writes channels sub*16 + g*2, +1 (full 256-B row per wave, coalesced)
  float o0 = acc[0], o1 = acc[1];
#pragma unroll
  for (int r = 1; r < 8; r++) {
    if (g == r) { o0 = acc[2 * r]; o1 = acc[2 * r + 1]; }
  }
  int ch = sub * 16 + g * 2;
  o0 = fmaxf(o0 * scale + bias[ch], 0.f);
  o1 = fmaxf(o1 * scale + bias[ch + 1], 0.f);
  f16x2 o;
  o[0] = (half_t)o0;
  o[1] = (half_t)o1;
  *(f16x2*)(out + (size_t)n * 128 + ch) = o;
}

// ============================ MFMA GEMM (half input, pre-transposed W) + logits ============================
__global__ __launch_bounds__(256) void k_gemm_att(const half_t* __restrict__ X, const half_t* __restrict__ WT,
                                                  const float* __restrict__ atts, const float* __restrict__ attd,
                                                  half_t* __restrict__ H, float* __restrict__ asrc,
                                                  float* __restrict__ adst) {
  __shared__ __align__(16) half_t Xt[128 * 40];
  __shared__ __align__(16) half_t Wt[128 * 40];
  int t = threadIdx.x;
  int wave = t >> 6, lane = t & 63;
  int l15 = lane & 15, quad = lane >> 4;
  int rb = blockIdx.x * 128;

  f32x4 acc[2][8];
#pragma unroll
  for (int rt = 0; rt < 2; rt++)
#pragma unroll
    for (int ct = 0; ct < 8; ct++) acc[rt][ct] = (f32x4){0.f, 0.f, 0.f, 0.f};

  for (int k0 = 0; k0 < 128; k0 += 32) {
    __syncthreads();
#pragma unroll
    for (int i = 0; i < 2; i++) {
      int lin = i * 256 + t;
      int row = lin >> 2;
      int c8 = (lin & 3) * 8;
      f16x8 hv = (f16x8)(half_t)0;
      int gr = rb + row;
      if (gr < NN) hv = *(const f16x8*)(X + (size_t)gr * 128 + k0 + c8);
      *(f16x8*)(Xt + row * 40 + c8) = hv;
    }
#pragma unroll
    for (int i = 0; i < 2; i++) {
      int lin = i * 256 + t;
      int row = lin >> 2;
      int c8 = (lin & 3) * 8;
      *(f16x8*)(Wt + row * 40 + c8) = *(const f16x8*)(WT + (size_t)row * 128 + k0 + c8);
    }
    __syncthreads();

    f16x8 a0 = *(const f16x8*)(Xt + (wave * 32 + l15) * 40 + quad * 8);
    f16x8 a1 = *(const f16x8*)(Xt + (wave * 32 + 16 + l15) * 40 + quad * 8);
#pragma unroll
    for (int ct = 0; ct < 8; ct++) {
      f16x8 b = *(const f16x8*)(Wt + (ct * 16 + l15) * 40 + quad * 8);
      acc[0][ct] = __builtin_amdgcn_mfma_f32_16x16x32_f16(a0, b, acc[0][ct], 0, 0, 0);
      acc[1][ct] = __builtin_amdgcn_mfma_f32_16x16x32_f16(a1, b, acc[1][ct], 0, 0, 0);
    }
  }

#pragma unroll
  for (int rt = 0; rt < 2; rt++) {
    int rbase = rb + wave * 32 + rt * 16 + quad * 4;
#pragma unroll
    for (int reg = 0; reg < 4; reg++) {
      int row = rbase + reg;
      if (row < NN) {
#pragma unroll
        for (int ct = 0; ct < 8; ct++) {
          H[(size_t)row * 128 + ct * 16 + l15] = (half_t)acc[rt][ct][reg];
        }
      }
    }
  }

  float s_lo[4], s_hi[4], d_lo[4], d_hi[4];
#pragma unroll
  for (int h = 0; h < 4; h++) {
    s_lo[h] = atts[h * 32 + l15];
    s_hi[h] = atts[h * 32 + 16 + l15];
    d_lo[h] = attd[h * 32 + l15];
    d_hi[h] = attd[h * 32 + 16 + l15];
  }
#pragma unroll
  for (int rt = 0; rt < 2; rt++) {
    float ps[4][4], pd[4][4];
#pragma unroll
    for (int reg = 0; reg < 4; reg++)
#pragma unroll
      for (int h = 0; h < 4; h++) {
        ps[reg][h] = acc[rt][2 * h][reg] * s_lo[h] + acc[rt][2 * h + 1][reg] * s_hi[h];
        pd[reg][h] = acc[rt][2 * h][reg] * d_lo[h] + acc[rt][2 * h + 1][reg] * d_hi[h];
      }
#pragma unroll
    for (int m = 1; m < 16; m <<= 1) {
#pragma unroll
      for (int reg = 0; reg < 4; reg++)
#pragma unroll
        for (int h = 0; h < 4; h++) {
          ps[reg][h] += __shfl_xor(ps[reg][h], m, 64);
          pd[reg][h] += __shfl_xor(pd[reg][h], m, 64);
        }
    }
    float vs = 0.f, vd = 0.f;
#pragma unroll
    for (int reg = 0; reg < 4; reg++)
#pragma unroll
      for (int h = 0; h < 4; h++) {
        if (l15 == reg * 4 + h) { vs = ps[reg][h]; vd = pd[reg][h]; }
      }
    int row = rb + wave * 32 + rt * 16 + quad * 4 + (l15 >> 2);
    int h = l15 & 3;
    if (row < NN) {
      asrc[row * 4 + h] = vs;
      adst[row * 4 + h] = vd;
    }
  }
}

// ============================ classifier (MFMA, Wc pre-transposed, N padded to 48) ============================
__global__ __launch_bounds__(256) void k_classifier(const half_t* __restrict__ Hf, const half_t* __restrict__ WTc,
                                                    const float* __restrict__ bc, float* __restrict__ out) {
  __shared__ __align__(16) half_t Xt[128 * 40];
  __shared__ __align__(16) half_t Wt[48 * 40];
  int t = threadIdx.x;
  int wave = t >> 6, lane = t & 63;
  int l15 = lane & 15, quad = lane >> 4;
  int rb = blockIdx.x * 128;

  f32x4 acc[2][3];
#pragma unroll
  for (int rt = 0; rt < 2; rt++)
#pragma unroll
    for (int ct = 0; ct < 3; ct++) acc[rt][ct] = (f32x4){0.f, 0.f, 0.f, 0.f};

  for (int k0 = 0; k0 < 128; k0 += 32) {
    __syncthreads();
#pragma unroll
    for (int i = 0; i < 2; i++) {
      int lin = i * 256 + t;
      int row = lin >> 2;
      int c8 = (lin & 3) * 8;
      f16x8 hv = (f16x8)(half_t)0;
      int gr = rb + row;
      if (gr < NN) hv = *(const f16x8*)(Hf + (size_t)gr * 128 + k0 + c8);
      *(f16x8*)(Xt + row * 40 + c8) = hv;
    }
    if (t < 192) {
      int row = t >> 2;
      int c8 = (t & 3) * 8;
      *(f16x8*)(Wt + row * 40 + c8) = *(const f16x8*)(WTc + (size_t)row * 128 + k0 + c8);
    }
    __syncthreads();

    f16x8 a0 = *(const f16x8*)(Xt + (wave * 32 + l15) * 40 + quad * 8);
    f16x8 a1 = *(const f16x8*)(Xt + (wave * 32 + 16 + l15) * 40 + quad * 8);
#pragma unroll
    for (int ct = 0; ct < 3; ct++) {
      f16x8 b = *(const f16x8*)(Wt + (ct * 16 + l15) * 40 + quad * 8);
      acc[0][ct] = __builtin_amdgcn_mfma_f32_16x16x32_f16(a0, b, acc[0][ct], 0, 0, 0);
      acc[1][ct] = __builtin_amdgcn_mfma_f32_16x16x32_f16(a1, b, acc[1][ct], 0, 0, 0);
    }
  }

#pragma unroll
  for (int rt = 0; rt < 2; rt++) {
#pragma unroll
    for (int ct = 0; ct < 3; ct++) {
      int col = ct * 16 + l15;
      if (col < 40) {
        float bv = bc[col];
#pragma unroll
        for (int reg = 0; reg < 4; reg++) {
          int row = rb + wave * 32 + rt * 16 + quad * 4 + reg;
          if (row < NN) out[(size_t)row * 40 + col] = acc[rt][ct][reg] + bv;
        }
      }
    }
  }
}

// ============================ launch ============================

extern "C" void kernel_launch(void* const* d_in, const int* in_sizes, int n_in,
                              void* d_out, int out_size, void* d_ws, size_t ws_size,
                              hipStream_t stream) {
  const float* x   = (const float*)d_in[0];
  const int*   ei  = (const int*)d_in[1];
  const float* W1  = (const float*)d_in[2];
  const float* as1 = (const float*)d_in[3];
  const float* ad1 = (const float*)d_in[4];
  const float* b1  = (const float*)d_in[5];
  const float* W2  = (const float*)d_in[6];
  const float* as2 = (const float*)d_in[7];
  const float* ad2 = (const float*)d_in[8];
  const float* b2  = (const float*)d_in[9];
  const float* Wc  = (const float*)d_in[10];
  const float* bc  = (const float*)d_in[11];
  float* out = (float*)d_out;

  const int* esrc = ei;
  const int* edst = ei + NE;

  char* w = (char*)d_ws;
  auto alloc = [&](size_t bytes) {
    void* p = (void*)w;
    w += (bytes + 255) & ~(size_t)255;
    return p;
  };
  half_t* A   = (half_t*)alloc(sizeof(half_t) * (size_t)NN * 128);  // gather target
  half_t* B   = (half_t*)alloc(sizeof(half_t) * (size_t)NN * 128);  // layer output
  float* asrc = (float*)alloc(sizeof(float) * (size_t)NN * 4);
  float* adst = (float*)alloc(sizeof(float) * (size_t)NN * 4);
  int* sbeg   = (int*)alloc(sizeof(int) * NN);
  int* send   = (int*)alloc(sizeof(int) * NN);
  unsigned int* bpk = (unsigned int*)alloc(sizeof(unsigned int) * (size_t)NBK * NBA * SCAP);
  int* bh     = (int*)alloc(sizeof(int) * NBK * NBA);
  int* adj    = (int*)alloc(sizeof(int) * (size_t)NBK * CAP2);
  half_t* WT2 = (half_t*)alloc(sizeof(half_t) * 128 * 128);
  half_t* WTc = (half_t*)alloc(sizeof(half_t) * 48 * 128);

  // ---- fused front: gemm1 + weight transposes + fixed-slot edge binning ----
  k_front<<<NBG + NPREP + NBA, 256, 0, stream>>>(x, W1, as1, ad1, A, asrc, adst,
                                                 W2, Wc, WT2, WTc, esrc, edst, bpk, bh);
  // ---- CSR finalize ----
  k_binB<<<NBK, 256, 0, stream>>>(bpk, bh, sbeg, send, adj);

  // ---- layer 1 aggregate ----
  k_agg<<<(NN + 3) / 4, 256, 0, stream>>>(A, sbeg, send, adj, asrc, adst, b1, B);

  // ---- layer 2 ----
  k_gemm_att<<<(NN + 127) / 128, 256, 0, stream>>>(B, WT2, as2, ad2, A, asrc, adst);
  k_agg<<<(NN + 3) / 4, 256, 0, stream>>>(A, sbeg, send, adj, asrc, adst, b2, B);

  // ---- classifier ----
  k_classifier<<<(NN + 127) / 128, 256, 0, stream>>>(B, WTc, bc, out);
}